// Round 4
// baseline (464.976 us; speedup 1.0000x reference)
//
#include <hip/hip_runtime.h>
#include <math.h>

#define HH 128
#define WW 128
#define HW 16384
#define BB 2
#define CC 192

typedef __attribute__((ext_vector_type(8))) short short8;
typedef __attribute__((ext_vector_type(4))) float f32x4;

// f32 -> bf16 bits, round-to-nearest-even
static __device__ __forceinline__ short f2bf(float f) {
    unsigned u = __float_as_uint(f);
    unsigned r = (u + 0x7FFFu + ((u >> 16) & 1u)) >> 16;
    return (short)r;
}
static __device__ __forceinline__ float bf2f(short s) {
    return __uint_as_float(((unsigned)(unsigned short)s) << 16);
}

// ---------------------------------------------------------------------------
// Channels-last transpose: xcat[b][pos][c2], c2 in [0,384): c2<192 -> x_vq,
// else x_res. bf16. Block: 64 px x 4 c-parts (256 thr); grid = B*HW/64.
// ---------------------------------------------------------------------------
__global__ __launch_bounds__(256) void to_cl_k(
    const float* __restrict__ xv, const float* __restrict__ xr,
    unsigned short* __restrict__ xcat)
{
    const int t   = threadIdx.x;
    const int lpx = t & 63;
    const int cp  = t >> 6;                       // 0..3 -> 96 channels each
    const int gpx = blockIdx.x * 64 + lpx;
    const int b   = gpx >> 14;
    const int pos = gpx & (HW - 1);
    unsigned short* dst = xcat + (size_t)gpx * 384 + cp * 96;

#pragma unroll
    for (int c8 = 0; c8 < 12; c8++) {
        const int c0 = cp * 96 + c8 * 8;
        short8 v;
#pragma unroll
        for (int r = 0; r < 8; r++) {
            const int c = c0 + r;
            const float f = (c < 192)
                ? xv[((size_t)(b * 192 + c) << 14) + pos]
                : xr[((size_t)(b * 192 + (c - 192)) << 14) + pos];
            v[r] = f2bf(f);
        }
        *reinterpret_cast<short8*>(dst + c8 * 8) = v;
    }
}

// ---------------------------------------------------------------------------
// Pack f32 weights into MFMA A-frag order, 3-level k decomposition:
// kg = chunk*32 + (lane>>4)*8 + r ; c1=kg/div1, c2=(kg%div1)>>5, c3=kg&31;
// src index = o*so + c1*sa + c2*sb + c3*sc. Layout
// wp[((mt*NQ + chunk)*64 + lane)*8 + r], o = mt*16+(lane&15). Zero-pad o>=Co.
// ---------------------------------------------------------------------------
__global__ void pack_w_k(const float* __restrict__ w, short* __restrict__ wp,
                         int Co, int Ktot, int MT,
                         int so, int div1, int sa, int sb, int sc)
{
    const int NQ = Ktot >> 5;
    const int total = MT * NQ * 64;
    int idx = blockIdx.x * blockDim.x + threadIdx.x;
    if (idx >= total) return;
    const int l     = idx & 63;
    const int chunk = (idx >> 6) % NQ;
    const int mt    = (idx >> 6) / NQ;
    const int o     = mt * 16 + (l & 15);
    const int kg0   = chunk * 32 + ((l >> 4) << 3);
    short8 v;
#pragma unroll
    for (int r = 0; r < 8; r++) {
        const int kg = kg0 + r;
        const int c1 = kg / div1;
        const int rem = kg % div1;
        float f = 0.f;
        if (o < Co) f = w[(size_t)o * so + c1 * sa + (rem >> 5) * sb + (rem & 31) * sc];
        v[r] = f2bf(f);
    }
    *reinterpret_cast<short8*>(wp + (size_t)idx * 8) = v;
}

// ---------------------------------------------------------------------------
// 3x3 conv (pad 1) as implicit GEMM over channels-last bf16 input.
// Block = 256 thr (4 waves); wave wn owns a 16-px n-tile; 64 px per (b,i,j0).
// k order: cq outer, tap inner (3x66px x 32ch window stays L1-resident over
// the 9 taps). B-frag = one per-lane b128 from xin (no LDS, no barriers).
// OUT_CL: bf16 channels-last (stride Cout) ; else: f32 planar NCHW.
// ---------------------------------------------------------------------------
template<int MT, int CIN, bool OUT_CL>
__global__ __launch_bounds__(256, 3) void conv_cl_k(
    const unsigned short* __restrict__ xin,
    const short* __restrict__ wA, const float* __restrict__ bias,
    void* __restrict__ outp, int Cout)
{
    const int t     = threadIdx.x;
    const int lane  = t & 63;
    const int wn    = t >> 6;
    const int j0    = blockIdx.x * 64;
    const int i     = blockIdx.y;
    const int b     = blockIdx.z;
    const int px_l  = (wn << 4) + (lane & 15);
    const int slot8 = (lane >> 4) << 3;
    constexpr int NQ = (CIN / 32) * 9;

    const unsigned short* xb = xin + (size_t)b * HW * CIN;

    f32x4 acc[MT];
#pragma unroll
    for (int mt = 0; mt < MT; mt++) acc[mt] = (f32x4){0.f, 0.f, 0.f, 0.f};

    for (int cq = 0; cq < CIN / 32; cq++) {
#pragma unroll
        for (int tap = 0; tap < 9; tap++) {
            const int dy = tap / 3 - 1, dx = tap % 3 - 1;
            const int iy = i + dy;
            const int jx = j0 + px_l + dx;
            const bool valid = ((unsigned)iy < HH) && ((unsigned)jx < WW);
            const int pos = (min(max(iy, 0), HH - 1) << 7) + min(max(jx, 0), WW - 1);
            short8 bF = *reinterpret_cast<const short8*>(
                xb + (size_t)pos * CIN + cq * 32 + slot8);
            if (!valid) {
#pragma unroll
                for (int r = 0; r < 8; r++) bF[r] = 0;
            }
            const int q = cq * 9 + tap;
            short8 aFv[MT];
#pragma unroll
            for (int mt = 0; mt < MT; mt++)
                aFv[mt] = *reinterpret_cast<const short8*>(
                    wA + ((size_t)((mt * NQ + q) * 64 + lane)) * 8);
#pragma unroll
            for (int mt = 0; mt < MT; mt++)
                acc[mt] = __builtin_amdgcn_mfma_f32_16x16x32_bf16(aFv[mt], bF, acc[mt], 0, 0, 0);
        }
    }

    // C/D: n = lane&15 -> px ; m = (lane>>4)*4 + jr -> out channel
    const int m4  = (lane >> 4) << 2;
    const int pos = (i << 7) + j0 + px_l;
    if constexpr (OUT_CL) {
        unsigned short* fcl = (unsigned short*)outp;
        unsigned short* dst = fcl + ((size_t)b * HW + pos) * (size_t)Cout;
#pragma unroll
        for (int mt = 0; mt < MT; mt++) {
            const int o0 = mt * 16 + m4;
            const unsigned p0 = (unsigned)(unsigned short)f2bf(acc[mt][0] + bias[o0 + 0]);
            const unsigned p1 = (unsigned)(unsigned short)f2bf(acc[mt][1] + bias[o0 + 1]);
            const unsigned p2 = (unsigned)(unsigned short)f2bf(acc[mt][2] + bias[o0 + 2]);
            const unsigned p3 = (unsigned)(unsigned short)f2bf(acc[mt][3] + bias[o0 + 3]);
            *reinterpret_cast<uint2*>(dst + o0) = make_uint2(p0 | (p1 << 16), p2 | (p3 << 16));
        }
    } else {
        float* outf = (float*)outp;
#pragma unroll
        for (int mt = 0; mt < MT; mt++)
#pragma unroll
            for (int jr = 0; jr < 4; jr++) {
                const int o = mt * 16 + m4 + jr;
                if (o < Cout)
                    outf[((size_t)(b * Cout + o) << 14) + pos] = acc[mt][jr] + bias[o];
            }
    }
}

// ---------------------------------------------------------------------------
// Fused deform-sample + einsum over channels-last bf16 x. Block = 256 thr
// (4 waves), out [192][64 px] per (b,i,j0). kgemm = kt*192 + c; a lane's 8
// channels never straddle a deform-group (48%8==0), so one entry per load.
// 4 b128 corner gathers per k-chunk; 2-deep ping-pong pipeline; no barriers
// in the K-loop.
// ---------------------------------------------------------------------------
__global__ __launch_bounds__(256, 2) void dcn_k(
    const unsigned short* __restrict__ xcat, const float* __restrict__ off,
    const short* __restrict__ wA, const float* __restrict__ bias,
    float* __restrict__ out)
{
    __shared__ __align__(16) f32x4 eW[2304];   // 36 KB  (4*9 gk x 64 px)
    __shared__ __align__(8)  uint2 eO[2304];   // 18 KB  packed corner positions

    const int t    = threadIdx.x;
    const int lane = t & 63;
    const int wid  = t >> 6;
    const int j0   = blockIdx.x * 64;
    const int i    = blockIdx.y;
    const int b    = blockIdx.z;

    // ---- A1: bilinear entries (identical math to verified rounds 2-3) ----
    for (int e = t; e < 2304; e += 256) {
        const int p  = e & 63;
        const int gk = e >> 6;               // g*9 + kt
        const int kt = gk % 9;
        const int j  = j0 + p;
        const size_t sp = (size_t)b * 108 * HW + (size_t)gk * HW + (i << 7) + j;
        const float dy = off[sp];
        const float dx = off[sp + (size_t)36 * HW];
        const float mv = off[sp + (size_t)72 * HW];
        const float m  = 1.f / (1.f + expf(-mv));
        const float py = (float)(i + kt / 3 - 1) + dy;
        const float px = (float)(j + kt % 3 - 1) + dx;
        const float y0f = floorf(py), x0f = floorf(px);
        const float ly = py - y0f, lx = px - x0f;
        const int y0 = (int)y0f, x0 = (int)x0f;
        const float vy0 = (y0 >= 0 && y0 < HH) ? 1.f : 0.f;
        const float vy1 = (y0 + 1 >= 0 && y0 + 1 < HH) ? 1.f : 0.f;
        const float vx0 = (x0 >= 0 && x0 < WW) ? 1.f : 0.f;
        const float vx1 = (x0 + 1 >= 0 && x0 + 1 < WW) ? 1.f : 0.f;
        f32x4 w4;
        w4[0] = (1.f - ly) * (1.f - lx) * m * vy0 * vx0;
        w4[1] = (1.f - ly) * lx         * m * vy0 * vx1;
        w4[2] = ly         * (1.f - lx) * m * vy1 * vx0;
        w4[3] = ly         * lx         * m * vy1 * vx1;
        const int yc0 = min(max(y0, 0), HH - 1);
        const int yc1 = min(max(y0 + 1, 0), HH - 1);
        const int xc0 = min(max(x0, 0), WW - 1);
        const int xc1 = min(max(x0 + 1, 0), WW - 1);
        eW[e] = w4;
        eO[e] = make_uint2((unsigned)((yc0 << 7) + xc0) | ((unsigned)((yc0 << 7) + xc1) << 16),
                           (unsigned)((yc1 << 7) + xc0) | ((unsigned)((yc1 << 7) + xc1) << 16));
    }
    __syncthreads();

    const int px_l  = (wid << 4) + (lane & 15);
    const int slot8 = (lane >> 4) << 3;
    const unsigned short* __restrict__ xcb = xcat + (size_t)b * HW * 384;

    f32x4 acc[12];
#pragma unroll
    for (int mt = 0; mt < 12; mt++) acc[mt] = (f32x4){0.f, 0.f, 0.f, 0.f};

#define DISSUE(Q, G0, G1, G2, G3, W4)                                         \
    {                                                                         \
        const int kt_ = (Q) / 6, cq_ = (Q) % 6;                               \
        const int cb_ = cq_ * 32 + slot8;                                     \
        const int e_  = (cb_ / 48) * 576 + kt_ * 64 + px_l;                   \
        const uint2 o_ = eO[e_];                                              \
        W4 = eW[e_];                                                          \
        const unsigned short* pb_ = xcb + cb_;                                \
        G0 = *reinterpret_cast<const short8*>(pb_ + (size_t)(o_.x & 0xFFFFu) * 384); \
        G1 = *reinterpret_cast<const short8*>(pb_ + (size_t)(o_.x >> 16)     * 384); \
        G2 = *reinterpret_cast<const short8*>(pb_ + (size_t)(o_.y & 0xFFFFu) * 384); \
        G3 = *reinterpret_cast<const short8*>(pb_ + (size_t)(o_.y >> 16)     * 384); \
    }

#define DCOMBINE(G0, G1, G2, G3, W4, BF)                                      \
    {                                                                         \
        _Pragma("unroll")                                                     \
        for (int r = 0; r < 8; r++) {                                         \
            const float v = W4[0] * bf2f(G0[r]) + W4[1] * bf2f(G1[r])         \
                          + W4[2] * bf2f(G2[r]) + W4[3] * bf2f(G3[r]);        \
            BF[r] = f2bf(v);                                                  \
        }                                                                     \
    }

#define DALOAD(Q, AFV)                                                        \
    {                                                                         \
        _Pragma("unroll")                                                     \
        for (int mt = 0; mt < 12; mt++)                                       \
            AFV[mt] = *reinterpret_cast<const short8*>(                       \
                wA + ((size_t)((mt * 54 + (Q)) * 64 + lane)) * 8);            \
    }

    short8 G0, G1, G2, G3, H0, H1, H2, H3;
    f32x4 wG, wH;

    DISSUE(0, G0, G1, G2, G3, wG);
    for (int q = 0; q < 54; q += 2) {
        short8 aFv[12];
        DISSUE(q + 1, H0, H1, H2, H3, wH);
        DALOAD(q, aFv);
        short8 bF;
        DCOMBINE(G0, G1, G2, G3, wG, bF);
#pragma unroll
        for (int mt = 0; mt < 12; mt++)
            acc[mt] = __builtin_amdgcn_mfma_f32_16x16x32_bf16(aFv[mt], bF, acc[mt], 0, 0, 0);

        if (q + 2 < 54) DISSUE(q + 2, G0, G1, G2, G3, wG);
        DALOAD(q + 1, aFv);
        short8 bF2;
        DCOMBINE(H0, H1, H2, H3, wH, bF2);
#pragma unroll
        for (int mt = 0; mt < 12; mt++)
            acc[mt] = __builtin_amdgcn_mfma_f32_16x16x32_bf16(aFv[mt], bF2, acc[mt], 0, 0, 0);
    }

    const int m4 = (lane >> 4) << 2;
#pragma unroll
    for (int mt = 0; mt < 12; mt++)
#pragma unroll
        for (int jr = 0; jr < 4; jr++) {
            const int o = mt * 16 + m4 + jr;
            out[((size_t)(b * CC + o) << 14) + (i << 7) + j0 + px_l] = acc[mt][jr] + bias[o];
        }
}

// ---------------------------------------------------------------------------
extern "C" void kernel_launch(void* const* d_in, const int* in_sizes, int n_in,
                              void* d_out, int out_size, void* d_ws, size_t ws_size,
                              hipStream_t stream)
{
    const float* x_vq  = (const float*)d_in[0];
    const float* x_res = (const float*)d_in[1];
    const float* w_off = (const float*)d_in[2];
    const float* b_off = (const float*)d_in[3];
    const float* w_co  = (const float*)d_in[4];
    const float* b_co  = (const float*)d_in[5];
    const float* w_dcn = (const float*)d_in[6];
    const float* b_dcn = (const float*)d_in[7];
    float* out = (float*)d_out;

    char* ws = (char*)d_ws;
    unsigned short* xcat = (unsigned short*)ws;                    // 25.17 MB
    const size_t xcat_sz = (size_t)BB * HW * 384 * 2;
    unsigned short* fcl  = (unsigned short*)(ws + xcat_sz);        // 12.58 MB
    const size_t fcl_sz  = (size_t)BB * HW * 192 * 2;
    float* offb = (float*)(ws + xcat_sz + fcl_sz);                 // 14.16 MB
    const size_t offb_sz = (size_t)BB * 108 * HW * 4;
    short* wA1 = (short*)(ws + xcat_sz + fcl_sz + offb_sz);        // 12*108*512
    short* wA2 = wA1 + (size_t)12 * 108 * 512;                     //  7*54*512
    short* wA3 = wA2 + (size_t)7 * 54 * 512;                       // 12*54*512

    // channels-last transpose of concat(x_vq, x_res)
    to_cl_k<<<dim3(BB * HW / 64), 256, 0, stream>>>(x_vq, x_res, xcat);

    // weight packing (kg decomposition documented at call site):
    // conv1/conv2: kg = cq*288 + tap*32 + c3 ; cin = cq*32+c3 ; w[o][cin][tap]
    pack_w_k<<<(12 * 108 * 64 + 255) / 256, 256, 0, stream>>>(w_off, wA1, 192, 3456, 12, 3456, 288, 288, 1, 9);
    pack_w_k<<<(7 * 54 * 64 + 255) / 256, 256, 0, stream>>>(w_co, wA2, 108, 1728, 7, 1728, 288, 288, 1, 9);
    // dcn: kg = kt*192 + cq*32 + c3 ; c = cq*32+c3 ; w[o][c][kt]
    pack_w_k<<<(12 * 54 * 64 + 255) / 256, 256, 0, stream>>>(w_dcn, wA3, 192, 1728, 12, 1728, 192, 1, 288, 9);

    dim3 grid(WW / 64, HH, BB);
    // conv1: xcat [384ch cl] -> fcl [192ch cl bf16]
    conv_cl_k<12, 384, true><<<grid, 256, 0, stream>>>(xcat, wA1, b_off, fcl, 192);
    // conv2: fcl [192ch cl] -> offb [108ch planar f32]
    conv_cl_k<7, 192, false><<<grid, 256, 0, stream>>>(fcl, wA2, b_co, offb, 108);
    // fused deform-sample + einsum
    dcn_k<<<grid, 256, 0, stream>>>(xcat, offb, wA3, b_dcn, out);
}

// Round 5
// 264.256 us; speedup vs baseline: 1.7596x; 1.7596x over previous
//
#include <hip/hip_runtime.h>
#include <math.h>

#define HH 128
#define WW 128
#define HW 16384
#define BB 2
#define CC 192

typedef __attribute__((ext_vector_type(8)))  short short8;
typedef __attribute__((ext_vector_type(4)))  float f32x4;
typedef __attribute__((ext_vector_type(16))) float f32x16;

// f32 -> bf16 bits, round-to-nearest-even
static __device__ __forceinline__ short f2bf(float f) {
    unsigned u = __float_as_uint(f);
    unsigned r = (u + 0x7FFFu + ((u >> 16) & 1u)) >> 16;
    return (short)r;
}
static __device__ __forceinline__ float bf2f(short s) {
    return __uint_as_float(((unsigned)(unsigned short)s) << 16);
}

// async global->LDS, 16B per lane. lds dest: wave-uniform base + lane*16.
static __device__ __forceinline__ void gl_lds16(const short* gsrc, short* ldst) {
    __builtin_amdgcn_global_load_lds(
        (const __attribute__((address_space(1))) unsigned*)gsrc,
        (__attribute__((address_space(3))) unsigned*)ldst, 16, 0, 0);
}

// ---------------------------------------------------------------------------
// Grouped channels-last transpose: xg[b][cg(48)][pos][8ch] bf16,
// channel c = cg*8+r: c<192 -> x_vq, else x_res.
// ---------------------------------------------------------------------------
__global__ __launch_bounds__(256) void to_grp_k(
    const float* __restrict__ xv, const float* __restrict__ xr,
    unsigned short* __restrict__ xg)
{
    const int idx = blockIdx.x * 256 + threadIdx.x;   // (b*48+cg)*HW + pos
    const int pos = idx & (HW - 1);
    const int cgb = idx >> 14;
    const int cg  = cgb % 48;
    const int b   = cgb / 48;
    short8 v;
#pragma unroll
    for (int r = 0; r < 8; r++) {
        const int c = cg * 8 + r;
        const float f = (c < 192)
            ? xv[((size_t)(b * 192 + c) << 14) + pos]
            : xr[((size_t)(b * 192 + (c - 192)) << 14) + pos];
        v[r] = f2bf(f);
    }
    *reinterpret_cast<short8*>(xg + (size_t)idx * 8) = v;
}

// ---------------------------------------------------------------------------
// Pack f32 weights into 32x32x16 A-frag chunks of 8 KB:
// wp[chunk*4096 + slot*512 + lane*8 + r], o = slot*32+(lane&31),
// k = chunk*16 + (lane>>5)*8 + r; src = w[o*so + (k/d1)*s1
//      + ((k%d1)/d2)*s2 + ((k%d1)%d2)*s3]. Zero-pad o >= Co.
// ---------------------------------------------------------------------------
__global__ void pack_w_k(const float* __restrict__ w, short* __restrict__ wp,
                         int Co, int so, int d1, int s1, int d2, int s2, int s3,
                         int total)
{
    const int idx = blockIdx.x * blockDim.x + threadIdx.x;
    if (idx >= total) return;
    const int lane  = idx & 63;
    const int slot  = (idx >> 6) & 7;
    const int chunk = idx >> 9;
    const int o     = slot * 32 + (lane & 31);
    const int k0    = chunk * 16 + ((lane >> 5) << 3);
    short8 v;
#pragma unroll
    for (int r = 0; r < 8; r++) {
        const int k = k0 + r;
        float f = 0.f;
        if (o < Co) {
            const int rem = k % d1;
            f = w[(size_t)o * so + (k / d1) * s1 + (rem / d2) * s2 + (rem % d2) * s3];
        }
        v[r] = f2bf(f);
    }
    *reinterpret_cast<short8*>(wp + (size_t)idx * 8) = v;
}

// ---------------------------------------------------------------------------
// 3x3 conv (pad 1), implicit GEMM, 32x32x16 MFMA, grouped-CL input.
// Block = 512 thr (8 waves) = one image row (128 px) x (MTW*2*32) out ch.
// Wave (mg = wid>>2, nt = wid&3): MTW m-tiles x 32 px. A streamed via
// global_load_lds, 3 buffers, 2 chunks ahead, counted vmcnt + raw barrier.
// ---------------------------------------------------------------------------
template<int MTW, int NC16, bool OUT_GRP>
__global__ __launch_bounds__(512) void conv_g_k(
    const unsigned short* __restrict__ xg,
    const short* __restrict__ wA, const float* __restrict__ bias,
    void* __restrict__ outp, int Cout)
{
    __shared__ __align__(16) short Abuf[3][4096];

    const int t    = threadIdx.x;
    const int lane = t & 63;
    const int wid  = t >> 6;
    const int mg   = wid >> 2;
    const int nt   = wid & 3;
    const int i    = blockIdx.x;
    const int b    = blockIdx.y;
    const int px   = (nt << 5) + (lane & 31);
    const int hi   = lane >> 5;
    constexpr int NQ = NC16 * 9;

    const unsigned short* __restrict__ xgb = xg + (size_t)b * (NC16 * 2) * HW * 8;

    f32x16 acc[MTW];
#pragma unroll
    for (int m = 0; m < MTW; m++)
#pragma unroll
        for (int r = 0; r < 16; r++) acc[m][r] = 0.f;

    // prologue: stage chunks 0,1
    gl_lds16(wA + (size_t)0 * 4096 + t * 8, &Abuf[0][wid * 512]);
    gl_lds16(wA + (size_t)1 * 4096 + t * 8, &Abuf[1][wid * 512]);
    asm volatile("s_waitcnt vmcnt(1)" ::: "memory");
    __builtin_amdgcn_s_barrier();
    __builtin_amdgcn_sched_barrier(0);

    int rb = 0;   // buffer holding current chunk
    for (int c16 = 0; c16 < NC16; c16++) {
#pragma unroll
        for (int tap = 0; tap < 9; tap++) {
            const int q = c16 * 9 + tap;
            // B fragment (issued before stage so its wait leaves stage in flight)
            const int iy = i + tap / 3 - 1;
            const int jx = px + tap % 3 - 1;
            const bool valid = ((unsigned)iy < HH) && ((unsigned)jx < WW);
            const int iyc = min(max(iy, 0), HH - 1);
            const int jxc = min(max(jx, 0), WW - 1);
            const int cg  = c16 * 2 + hi;
            short8 bF = *reinterpret_cast<const short8*>(
                xgb + ((size_t)cg * HW + (iyc << 7) + jxc) * 8);
            if (!valid) {
#pragma unroll
                for (int r = 0; r < 8; r++) bF[r] = 0;
            }
            // stage chunk q+2
            if (q + 2 < NQ) {
                const int sb = rb >= 1 ? rb - 1 : 2;   // (rb+2)%3
                gl_lds16(wA + (size_t)(q + 2) * 4096 + t * 8, &Abuf[sb][wid * 512]);
            }
            // A fragments + MFMA
            short8 aF[MTW];
#pragma unroll
            for (int m = 0; m < MTW; m++)
                aF[m] = *reinterpret_cast<const short8*>(
                    &Abuf[rb][(mg * MTW + m) * 512 + lane * 8]);
#pragma unroll
            for (int m = 0; m < MTW; m++)
                acc[m] = __builtin_amdgcn_mfma_f32_32x32x16_bf16(aF[m], bF, acc[m], 0, 0, 0);

            asm volatile("s_waitcnt vmcnt(1)" ::: "memory"); // chunk q+1 landed
            __builtin_amdgcn_s_barrier();
            __builtin_amdgcn_sched_barrier(0);
            rb = rb == 2 ? 0 : rb + 1;
        }
    }

    // store. C/D: col = lane&31 -> px ; row = (reg&3)+8*(reg>>2)+4*hi -> o.
    const int pos_o = (i << 7) + px;
    if constexpr (OUT_GRP) {
        unsigned short* fg = (unsigned short*)outp;
#pragma unroll
        for (int m = 0; m < MTW; m++) {
            const int mt32 = mg * MTW + m;
#pragma unroll
            for (int g = 0; g < 4; g++) {
                const int ob = mt32 * 32 + 8 * g + 4 * hi;
                const unsigned s0 = (unsigned short)f2bf(acc[m][4 * g + 0] + bias[ob + 0]);
                const unsigned s1 = (unsigned short)f2bf(acc[m][4 * g + 1] + bias[ob + 1]);
                const unsigned s2 = (unsigned short)f2bf(acc[m][4 * g + 2] + bias[ob + 2]);
                const unsigned s3 = (unsigned short)f2bf(acc[m][4 * g + 3] + bias[ob + 3]);
                const int cg = mt32 * 4 + g;
                *reinterpret_cast<uint2*>(
                    fg + ((size_t)(b * (Cout >> 3) + cg) * HW + pos_o) * 8 + 4 * hi) =
                    make_uint2(s0 | (s1 << 16), s2 | (s3 << 16));
            }
        }
    } else {
        float* of = (float*)outp;
#pragma unroll
        for (int m = 0; m < MTW; m++) {
            const int mt32 = mg * MTW + m;
#pragma unroll
            for (int reg = 0; reg < 16; reg++) {
                const int o = mt32 * 32 + (reg & 3) + ((reg >> 2) << 3) + (hi << 2);
                if (o < Cout)
                    of[((size_t)(b * Cout + o) << 14) + pos_o] = acc[m][reg] + bias[o];
            }
        }
    }
}

// ---------------------------------------------------------------------------
// Fused deform-sample + einsum, 32x32x16 MFMA, grouped-CL x, streamed A.
// Block = 256 thr (4 waves; mg = wid>>1, nt = wid&1), 192 o x 64 px per
// (b,i,j0). chunk q = kt*12 + c16; lane's 8 ch = cg (c16*2+hi), one entry
// (g = c16/3 uniform). 4 corner b128 gathers per chunk.
// ---------------------------------------------------------------------------
__global__ __launch_bounds__(256) void dcn_g_k(
    const unsigned short* __restrict__ xg, const float* __restrict__ off,
    const short* __restrict__ wA, const float* __restrict__ bias,
    float* __restrict__ out)
{
    __shared__ __align__(16) f32x4 eW[2304];      // 36 KB
    __shared__ __align__(8)  uint2 eO[2304];      // 18 KB
    __shared__ __align__(16) short Abuf[3][4096]; // 24 KB

    const int t    = threadIdx.x;
    const int lane = t & 63;
    const int wid  = t >> 6;
    const int mg   = wid >> 1;
    const int nt   = wid & 1;
    const int j0   = blockIdx.x * 64;
    const int i    = blockIdx.y;
    const int b    = blockIdx.z;

    // ---- A1: bilinear entries (identical math to verified rounds 2-4) ----
    for (int e = t; e < 2304; e += 256) {
        const int p  = e & 63;
        const int gk = e >> 6;               // g*9 + kt
        const int kt = gk % 9;
        const int j  = j0 + p;
        const size_t sp = (size_t)b * 108 * HW + (size_t)gk * HW + (i << 7) + j;
        const float dy = off[sp];
        const float dx = off[sp + (size_t)36 * HW];
        const float mv = off[sp + (size_t)72 * HW];
        const float m  = 1.f / (1.f + expf(-mv));
        const float py = (float)(i + kt / 3 - 1) + dy;
        const float px = (float)(j + kt % 3 - 1) + dx;
        const float y0f = floorf(py), x0f = floorf(px);
        const float ly = py - y0f, lx = px - x0f;
        const int y0 = (int)y0f, x0 = (int)x0f;
        const float vy0 = (y0 >= 0 && y0 < HH) ? 1.f : 0.f;
        const float vy1 = (y0 + 1 >= 0 && y0 + 1 < HH) ? 1.f : 0.f;
        const float vx0 = (x0 >= 0 && x0 < WW) ? 1.f : 0.f;
        const float vx1 = (x0 + 1 >= 0 && x0 + 1 < WW) ? 1.f : 0.f;
        f32x4 w4;
        w4[0] = (1.f - ly) * (1.f - lx) * m * vy0 * vx0;
        w4[1] = (1.f - ly) * lx         * m * vy0 * vx1;
        w4[2] = ly         * (1.f - lx) * m * vy1 * vx0;
        w4[3] = ly         * lx         * m * vy1 * vx1;
        const int yc0 = min(max(y0, 0), HH - 1);
        const int yc1 = min(max(y0 + 1, 0), HH - 1);
        const int xc0 = min(max(x0, 0), WW - 1);
        const int xc1 = min(max(x0 + 1, 0), WW - 1);
        eW[e] = w4;
        eO[e] = make_uint2((unsigned)((yc0 << 7) + xc0) | ((unsigned)((yc0 << 7) + xc1) << 16),
                           (unsigned)((yc1 << 7) + xc0) | ((unsigned)((yc1 << 7) + xc1) << 16));
    }

    // prologue: stage chunks 0,1 (2 loads per thread each)
    gl_lds16(wA + (size_t)0 * 4096 + t * 8,          &Abuf[0][wid * 512]);
    gl_lds16(wA + (size_t)0 * 4096 + (t + 256) * 8,  &Abuf[0][2048 + wid * 512]);
    gl_lds16(wA + (size_t)1 * 4096 + t * 8,          &Abuf[1][wid * 512]);
    gl_lds16(wA + (size_t)1 * 4096 + (t + 256) * 8,  &Abuf[1][2048 + wid * 512]);
    asm volatile("s_waitcnt vmcnt(2) lgkmcnt(0)" ::: "memory");
    __builtin_amdgcn_s_barrier();
    __builtin_amdgcn_sched_barrier(0);

    const int px_l = (nt << 5) + (lane & 31);
    const int hi   = lane >> 5;
    const unsigned short* __restrict__ xgb = xg + (size_t)b * 48 * HW * 8;

    f32x16 acc[3];
#pragma unroll
    for (int m = 0; m < 3; m++)
#pragma unroll
        for (int r = 0; r < 16; r++) acc[m][r] = 0.f;

    int rb = 0;
    for (int kt = 0; kt < 9; kt++) {
        for (int c16 = 0; c16 < 12; c16++) {
            const int q = kt * 12 + c16;
            // entry + 4 corner gathers (issued before stage)
            const int g = c16 / 3;
            const int e = (g * 9 + kt) * 64 + px_l;
            const uint2 o_ = eO[e];
            const f32x4 w4 = eW[e];
            const int cg = c16 * 2 + hi;
            const unsigned short* base = xgb + (size_t)cg * HW * 8;
            const short8 G0 = *reinterpret_cast<const short8*>(base + (size_t)(o_.x & 0xFFFFu) * 8);
            const short8 G1 = *reinterpret_cast<const short8*>(base + (size_t)(o_.x >> 16) * 8);
            const short8 G2 = *reinterpret_cast<const short8*>(base + (size_t)(o_.y & 0xFFFFu) * 8);
            const short8 G3 = *reinterpret_cast<const short8*>(base + (size_t)(o_.y >> 16) * 8);
            // stage chunk q+2
            if (q + 2 < 108) {
                const int sb = rb >= 1 ? rb - 1 : 2;
                gl_lds16(wA + (size_t)(q + 2) * 4096 + t * 8,         &Abuf[sb][wid * 512]);
                gl_lds16(wA + (size_t)(q + 2) * 4096 + (t + 256) * 8, &Abuf[sb][2048 + wid * 512]);
            }
            // bilinear combine -> bf16 B fragment
            short8 bF;
#pragma unroll
            for (int r = 0; r < 8; r++) {
                const float v = w4[0] * bf2f(G0[r]) + w4[1] * bf2f(G1[r])
                              + w4[2] * bf2f(G2[r]) + w4[3] * bf2f(G3[r]);
                bF[r] = f2bf(v);
            }
            short8 aF[3];
#pragma unroll
            for (int m = 0; m < 3; m++)
                aF[m] = *reinterpret_cast<const short8*>(
                    &Abuf[rb][(mg * 3 + m) * 512 + lane * 8]);
#pragma unroll
            for (int m = 0; m < 3; m++)
                acc[m] = __builtin_amdgcn_mfma_f32_32x32x16_bf16(aF[m], bF, acc[m], 0, 0, 0);

            asm volatile("s_waitcnt vmcnt(2)" ::: "memory"); // chunk q+1 landed
            __builtin_amdgcn_s_barrier();
            __builtin_amdgcn_sched_barrier(0);
            rb = rb == 2 ? 0 : rb + 1;
        }
    }

    const int pos_o = (i << 7) + j0 + px_l;
#pragma unroll
    for (int m = 0; m < 3; m++) {
        const int mt32 = mg * 3 + m;
#pragma unroll
        for (int reg = 0; reg < 16; reg++) {
            const int o = mt32 * 32 + (reg & 3) + ((reg >> 2) << 3) + (hi << 2);
            out[((size_t)(b * CC + o) << 14) + pos_o] = acc[m][reg] + bias[o];
        }
    }
}

// ---------------------------------------------------------------------------
extern "C" void kernel_launch(void* const* d_in, const int* in_sizes, int n_in,
                              void* d_out, int out_size, void* d_ws, size_t ws_size,
                              hipStream_t stream)
{
    const float* x_vq  = (const float*)d_in[0];
    const float* x_res = (const float*)d_in[1];
    const float* w_off = (const float*)d_in[2];
    const float* b_off = (const float*)d_in[3];
    const float* w_co  = (const float*)d_in[4];
    const float* b_co  = (const float*)d_in[5];
    const float* w_dcn = (const float*)d_in[6];
    const float* b_dcn = (const float*)d_in[7];
    float* out = (float*)d_out;

    char* ws = (char*)d_ws;
    unsigned short* xg = (unsigned short*)ws;                      // 25.17 MB
    const size_t xg_sz = (size_t)BB * 48 * HW * 8 * 2;
    unsigned short* fg = (unsigned short*)(ws + xg_sz);            // 12.58 MB
    const size_t fg_sz = (size_t)BB * 24 * HW * 8 * 2;
    float* offb = (float*)(ws + xg_sz + fg_sz);                    // 14.16 MB
    const size_t offb_sz = (size_t)BB * 108 * HW * 4;
    short* wA1 = (short*)(ws + xg_sz + fg_sz + offb_sz);           // 216*4096
    short* wA2 = wA1 + (size_t)216 * 4096;                         // 108*4096
    short* wA3 = wA2 + (size_t)108 * 4096;                         // 108*4096

    to_grp_k<<<dim3(BB * 48 * HW / 256), 256, 0, stream>>>(x_vq, x_res, xg);

    // packing. conv: k = c16*144 + tap*16 + cl -> w[o][c16*16+cl][tap]
    //          (d1=144,s1=144,d2=16,s2=1,s3=9)
    pack_w_k<<<(216 * 512 + 255) / 256, 256, 0, stream>>>(
        w_off, wA1, 192, 3456, 144, 144, 16, 1, 9, 216 * 512);
    pack_w_k<<<(108 * 512 + 255) / 256, 256, 0, stream>>>(
        w_co, wA2, 108, 1728, 144, 144, 16, 1, 9, 108 * 512);
    // dcn: k = kt*192 + c -> w[o][c][kt]  (d1=192,s1=1,d2=192,s2=0,s3=9)
    pack_w_k<<<(108 * 512 + 255) / 256, 256, 0, stream>>>(
        w_dcn, wA3, 192, 1728, 192, 1, 192, 0, 9, 108 * 512);

    // conv1: xg [48 grp] -> fg [24 grp bf16]
    conv_g_k<3, 24, true><<<dim3(HH, BB), 512, 0, stream>>>(xg, wA1, b_off, fg, 192);
    // conv2: fg [24 grp] -> offb [108 planar f32]
    conv_g_k<2, 12, false><<<dim3(HH, BB), 512, 0, stream>>>(fg, wA2, b_co, offb, 108);
    // fused deform-sample + einsum
    dcn_g_k<<<dim3(2, HH, BB), 256, 0, stream>>>(xg, offb, wA3, b_dcn, out);
}

// Round 6
// 252.245 us; speedup vs baseline: 1.8434x; 1.0476x over previous
//
#include <hip/hip_runtime.h>
#include <math.h>

#define HH 128
#define WW 128
#define HW 16384
#define BB 2
#define CC 192

typedef __attribute__((ext_vector_type(8)))  short short8;
typedef __attribute__((ext_vector_type(4)))  float f32x4;
typedef __attribute__((ext_vector_type(16))) float f32x16;

// f32 -> bf16 bits, round-to-nearest-even
static __device__ __forceinline__ short f2bf(float f) {
    unsigned u = __float_as_uint(f);
    unsigned r = (u + 0x7FFFu + ((u >> 16) & 1u)) >> 16;
    return (short)r;
}
static __device__ __forceinline__ float bf2f(short s) {
    return __uint_as_float(((unsigned)(unsigned short)s) << 16);
}

// async global->LDS, 16B per lane. lds dest: wave-uniform base + lane*16.
static __device__ __forceinline__ void gl_lds16(const short* gsrc, short* ldst) {
    __builtin_amdgcn_global_load_lds(
        (const __attribute__((address_space(1))) unsigned*)gsrc,
        (__attribute__((address_space(3))) unsigned*)ldst, 16, 0, 0);
}

// ---------------------------------------------------------------------------
// Grouped channels-last transpose: xg[b][cg(48)][pos][8ch] bf16.
// ---------------------------------------------------------------------------
__global__ __launch_bounds__(256) void to_grp_k(
    const float* __restrict__ xv, const float* __restrict__ xr,
    unsigned short* __restrict__ xg)
{
    const int idx = blockIdx.x * 256 + threadIdx.x;   // (b*48+cg)*HW + pos
    const int pos = idx & (HW - 1);
    const int cgb = idx >> 14;
    const int cg  = cgb % 48;
    const int b   = cgb / 48;
    short8 v;
#pragma unroll
    for (int r = 0; r < 8; r++) {
        const int c = cg * 8 + r;
        const float f = (c < 192)
            ? xv[((size_t)(b * 192 + c) << 14) + pos]
            : xr[((size_t)(b * 192 + (c - 192)) << 14) + pos];
        v[r] = f2bf(f);
    }
    *reinterpret_cast<short8*>(xg + (size_t)idx * 8) = v;
}

// ---------------------------------------------------------------------------
// Pack f32 weights into 32x32x16 A-frag chunks of 8 KB:
// wp[chunk*4096 + slot*512 + lane*8 + r], o = slot*32+(lane&31),
// k = chunk*16 + (lane>>5)*8 + r; src = w[o*so + (k/d1)*s1
//      + ((k%d1)/d2)*s2 + ((k%d1)%d2)*s3]. Zero-pad o >= Co.
// ---------------------------------------------------------------------------
__global__ void pack_w_k(const float* __restrict__ w, short* __restrict__ wp,
                         int Co, int so, int d1, int s1, int d2, int s2, int s3,
                         int total)
{
    const int idx = blockIdx.x * blockDim.x + threadIdx.x;
    if (idx >= total) return;
    const int lane  = idx & 63;
    const int slot  = (idx >> 6) & 7;
    const int chunk = idx >> 9;
    const int o     = slot * 32 + (lane & 31);
    const int k0    = chunk * 16 + ((lane >> 5) << 3);
    short8 v;
#pragma unroll
    for (int r = 0; r < 8; r++) {
        const int k = k0 + r;
        float f = 0.f;
        if (o < Co) {
            const int rem = k % d1;
            f = w[(size_t)o * so + (k / d1) * s1 + (rem / d2) * s2 + (rem % d2) * s3];
        }
        v[r] = f2bf(f);
    }
    *reinterpret_cast<short8*>(wp + (size_t)idx * 8) = v;
}

// ---------------------------------------------------------------------------
// 3x3 conv (pad 1), implicit GEMM, 32x32x16 MFMA, grouped-CL input.
// Block = 512 thr (8 waves) = one image row (128 px) x (MTW*2*32) out ch.
// Pipeline per iter q: load B_{q+1} to reg; vmcnt(N); barrier; stage A chunk
// q+3 (global_load_lds, 4 buffers); ds_read A of q; MFMA with B_q.
// Exact counted vmcnt incl. drained tail. XCD-swizzled rows.
// ---------------------------------------------------------------------------
template<int MTW, int NC16, bool OUT_GRP>
__global__ __launch_bounds__(512) void conv_g_k(
    const unsigned short* __restrict__ xg,
    const short* __restrict__ wA, const float* __restrict__ bias,
    void* __restrict__ outp, int Cout)
{
    __shared__ __align__(16) short Abuf[4][4096];

    const int t    = threadIdx.x;
    const int lane = t & 63;
    const int wid  = t >> 6;
    const int mg   = wid >> 2;
    const int nt   = wid & 3;
    // XCD swizzle: nwg = 128*BB (div by 8); contiguous rows per XCD
    const int lin  = blockIdx.y * HH + blockIdx.x;
    const int og_  = (lin & 7) * ((HH * BB) >> 3) + (lin >> 3);
    const int i    = og_ % HH;
    const int b    = og_ / HH;
    const int px   = (nt << 5) + (lane & 31);
    const int hi   = lane >> 5;
    constexpr int NQ = NC16 * 9;

    const unsigned short* __restrict__ xgb = xg + (size_t)b * (NC16 * 2) * HW * 8;

    f32x16 acc[MTW];
#pragma unroll
    for (int m = 0; m < MTW; m++)
#pragma unroll
        for (int r = 0; r < 16; r++) acc[m][r] = 0.f;

    auto loadB = [&](int qq, short8& dst, bool& vm) {
        const int c16 = qq / 9;
        const int tap = qq - c16 * 9;
        const int iy  = i + tap / 3 - 1;
        const int jx  = px + tap % 3 - 1;
        vm = ((unsigned)iy < HH) && ((unsigned)jx < WW);
        const int iyc = min(max(iy, 0), HH - 1);
        const int jxc = min(max(jx, 0), WW - 1);
        const int cg  = c16 * 2 + hi;
        dst = *reinterpret_cast<const short8*>(
            xgb + ((size_t)cg * HW + (iyc << 7) + jxc) * 8);
    };

    short8 bA, bB;
    bool mA = false, mB = false;

    // prologue: B_0 then stage chunks 0,1,2
    loadB(0, bA, mA);
    gl_lds16(wA + (size_t)0 * 4096 + t * 8, &Abuf[0][wid * 512]);
    gl_lds16(wA + (size_t)1 * 4096 + t * 8, &Abuf[1][wid * 512]);
    gl_lds16(wA + (size_t)2 * 4096 + t * 8, &Abuf[2][wid * 512]);

#define CSTEP(Q, VM, DOB, DOS, BC, MC, BN, MN)                                \
    {                                                                         \
        if (DOB) loadB((Q) + 1, BN, MN);                                      \
        asm volatile("s_waitcnt vmcnt(" #VM ")" ::: "memory");                \
        __builtin_amdgcn_s_barrier();                                         \
        __builtin_amdgcn_sched_barrier(0);                                    \
        if (DOS) gl_lds16(wA + (size_t)((Q) + 3) * 4096 + t * 8,              \
                          &Abuf[((Q) + 3) & 3][wid * 512]);                   \
        short8 bF = BC;                                                       \
        if (!MC) {                                                            \
            _Pragma("unroll")                                                 \
            for (int r = 0; r < 8; r++) bF[r] = 0;                            \
        }                                                                     \
        const short* ab = &Abuf[(Q) & 3][(mg * MTW) * 512 + lane * 8];        \
        short8 aF[MTW];                                                       \
        _Pragma("unroll")                                                     \
        for (int m = 0; m < MTW; m++)                                         \
            aF[m] = *reinterpret_cast<const short8*>(ab + m * 512);           \
        _Pragma("unroll")                                                     \
        for (int m = 0; m < MTW; m++)                                         \
            acc[m] = __builtin_amdgcn_mfma_f32_32x32x16_bf16(aF[m], bF, acc[m], 0, 0, 0); \
    }

    CSTEP(0, 3, true, true, bA, mA, bB, mB);
    for (int q = 1; q + 3 < NQ; q += 2) {
        CSTEP(q, 2, true, true, bB, mB, bA, mA);
        CSTEP(q + 1, 2, true, true, bA, mA, bB, mB);
    }
    CSTEP(NQ - 3, 2, true, false, bB, mB, bA, mA);
    CSTEP(NQ - 2, 1, true, false, bA, mA, bB, mB);
    CSTEP(NQ - 1, 0, false, false, bB, mB, bA, mA);
#undef CSTEP

    // store. C/D: col = lane&31 -> px ; row = (reg&3)+8*(reg>>2)+4*hi -> o.
    const int pos_o = (i << 7) + px;
    if constexpr (OUT_GRP) {
        unsigned short* fg = (unsigned short*)outp;
#pragma unroll
        for (int m = 0; m < MTW; m++) {
            const int mt32 = mg * MTW + m;
#pragma unroll
            for (int g = 0; g < 4; g++) {
                const int ob = mt32 * 32 + 8 * g + 4 * hi;
                const unsigned s0 = (unsigned short)f2bf(acc[m][4 * g + 0] + bias[ob + 0]);
                const unsigned s1 = (unsigned short)f2bf(acc[m][4 * g + 1] + bias[ob + 1]);
                const unsigned s2 = (unsigned short)f2bf(acc[m][4 * g + 2] + bias[ob + 2]);
                const unsigned s3 = (unsigned short)f2bf(acc[m][4 * g + 3] + bias[ob + 3]);
                const int cg = mt32 * 4 + g;
                *reinterpret_cast<uint2*>(
                    fg + ((size_t)(b * (Cout >> 3) + cg) * HW + pos_o) * 8 + 4 * hi) =
                    make_uint2(s0 | (s1 << 16), s2 | (s3 << 16));
            }
        }
    } else {
        float* of = (float*)outp;
#pragma unroll
        for (int m = 0; m < MTW; m++) {
            const int mt32 = mg * MTW + m;
#pragma unroll
            for (int reg = 0; reg < 16; reg++) {
                const int o = mt32 * 32 + (reg & 3) + ((reg >> 2) << 3) + (hi << 2);
                if (o < Cout)
                    of[((size_t)(b * Cout + o) << 14) + pos_o] = acc[m][reg] + bias[o];
            }
        }
    }
}

// ---------------------------------------------------------------------------
// Fused deform-sample + einsum, 32x32x16 MFMA, grouped-CL x, streamed A.
// Block = 256 thr (4 waves), 192 o x 64 px per (b,i,j0).
// Chunk order: c16 OUTER, kt inner (q = c16*9+kt) -> the 9 taps of a channel
// group hit the same spatial neighborhood back-to-back (x read ~once from
// HBM instead of 9x). Weights packed to match. XCD-swizzled rows.
// ---------------------------------------------------------------------------
__global__ __launch_bounds__(256) void dcn_g_k(
    const unsigned short* __restrict__ xg, const float* __restrict__ off,
    const short* __restrict__ wA, const float* __restrict__ bias,
    float* __restrict__ out)
{
    __shared__ __align__(16) f32x4 eW[2304];      // 36 KB
    __shared__ __align__(8)  uint2 eO[2304];      // 18 KB
    __shared__ __align__(16) short Abuf[3][4096]; // 24 KB

    const int t    = threadIdx.x;
    const int lane = t & 63;
    const int wid  = t >> 6;
    const int mg   = wid >> 1;
    const int nt   = wid & 1;
    // XCD swizzle: nwg = 2*128*BB = 512; 64 consecutive (jh,i) per XCD
    const int lin  = (blockIdx.z * HH + blockIdx.y) * 2 + blockIdx.x;
    const int og_  = (lin & 7) * 64 + (lin >> 3);
    const int j0   = (og_ & 1) * 64;
    const int i    = (og_ >> 1) & (HH - 1);
    const int b    = og_ >> 8;

    // ---- A1: bilinear entries (identical math to verified rounds 2-5) ----
    for (int e = t; e < 2304; e += 256) {
        const int p  = e & 63;
        const int gk = e >> 6;               // g*9 + kt
        const int kt = gk % 9;
        const int j  = j0 + p;
        const size_t sp = (size_t)b * 108 * HW + (size_t)gk * HW + (i << 7) + j;
        const float dy = off[sp];
        const float dx = off[sp + (size_t)36 * HW];
        const float mv = off[sp + (size_t)72 * HW];
        const float m  = 1.f / (1.f + expf(-mv));
        const float py = (float)(i + kt / 3 - 1) + dy;
        const float px = (float)(j + kt % 3 - 1) + dx;
        const float y0f = floorf(py), x0f = floorf(px);
        const float ly = py - y0f, lx = px - x0f;
        const int y0 = (int)y0f, x0 = (int)x0f;
        const float vy0 = (y0 >= 0 && y0 < HH) ? 1.f : 0.f;
        const float vy1 = (y0 + 1 >= 0 && y0 + 1 < HH) ? 1.f : 0.f;
        const float vx0 = (x0 >= 0 && x0 < WW) ? 1.f : 0.f;
        const float vx1 = (x0 + 1 >= 0 && x0 + 1 < WW) ? 1.f : 0.f;
        f32x4 w4;
        w4[0] = (1.f - ly) * (1.f - lx) * m * vy0 * vx0;
        w4[1] = (1.f - ly) * lx         * m * vy0 * vx1;
        w4[2] = ly         * (1.f - lx) * m * vy1 * vx0;
        w4[3] = ly         * lx         * m * vy1 * vx1;
        const int yc0 = min(max(y0, 0), HH - 1);
        const int yc1 = min(max(y0 + 1, 0), HH - 1);
        const int xc0 = min(max(x0, 0), WW - 1);
        const int xc1 = min(max(x0 + 1, 0), WW - 1);
        eW[e] = w4;
        eO[e] = make_uint2((unsigned)((yc0 << 7) + xc0) | ((unsigned)((yc0 << 7) + xc1) << 16),
                           (unsigned)((yc1 << 7) + xc0) | ((unsigned)((yc1 << 7) + xc1) << 16));
    }

    // prologue: stage chunks 0,1 (2 loads per thread each)
    gl_lds16(wA + (size_t)0 * 4096 + t * 8,          &Abuf[0][wid * 512]);
    gl_lds16(wA + (size_t)0 * 4096 + (t + 256) * 8,  &Abuf[0][2048 + wid * 512]);
    gl_lds16(wA + (size_t)1 * 4096 + t * 8,          &Abuf[1][wid * 512]);
    gl_lds16(wA + (size_t)1 * 4096 + (t + 256) * 8,  &Abuf[1][2048 + wid * 512]);
    asm volatile("s_waitcnt vmcnt(2) lgkmcnt(0)" ::: "memory");
    __builtin_amdgcn_s_barrier();
    __builtin_amdgcn_sched_barrier(0);

    const int px_l = (nt << 5) + (lane & 31);
    const int hi   = lane >> 5;
    const unsigned short* __restrict__ xgb = xg + (size_t)b * 48 * HW * 8;

    f32x16 acc[3];
#pragma unroll
    for (int m = 0; m < 3; m++)
#pragma unroll
        for (int r = 0; r < 16; r++) acc[m][r] = 0.f;

    int rb = 0;
    for (int c16 = 0; c16 < 12; c16++) {
        const int g  = c16 / 3;
        const int cg = c16 * 2 + hi;
        const unsigned short* base = xgb + (size_t)cg * HW * 8;
#pragma unroll
        for (int kt = 0; kt < 9; kt++) {
            const int q = c16 * 9 + kt;
            // entry + 4 corner gathers (issued before stage)
            const int e = (g * 9 + kt) * 64 + px_l;
            const uint2 o_ = eO[e];
            const f32x4 w4 = eW[e];
            const short8 G0 = *reinterpret_cast<const short8*>(base + (size_t)(o_.x & 0xFFFFu) * 8);
            const short8 G1 = *reinterpret_cast<const short8*>(base + (size_t)(o_.x >> 16) * 8);
            const short8 G2 = *reinterpret_cast<const short8*>(base + (size_t)(o_.y & 0xFFFFu) * 8);
            const short8 G3 = *reinterpret_cast<const short8*>(base + (size_t)(o_.y >> 16) * 8);
            // stage chunk q+2
            if (q + 2 < 108) {
                const int sb = rb >= 1 ? rb - 1 : 2;
                gl_lds16(wA + (size_t)(q + 2) * 4096 + t * 8,         &Abuf[sb][wid * 512]);
                gl_lds16(wA + (size_t)(q + 2) * 4096 + (t + 256) * 8, &Abuf[sb][2048 + wid * 512]);
            }
            // bilinear combine -> bf16 B fragment
            short8 bF;
#pragma unroll
            for (int r = 0; r < 8; r++) {
                const float v = w4[0] * bf2f(G0[r]) + w4[1] * bf2f(G1[r])
                              + w4[2] * bf2f(G2[r]) + w4[3] * bf2f(G3[r]);
                bF[r] = f2bf(v);
            }
            short8 aF[3];
#pragma unroll
            for (int m = 0; m < 3; m++)
                aF[m] = *reinterpret_cast<const short8*>(
                    &Abuf[rb][(mg * 3 + m) * 512 + lane * 8]);
#pragma unroll
            for (int m = 0; m < 3; m++)
                acc[m] = __builtin_amdgcn_mfma_f32_32x32x16_bf16(aF[m], bF, acc[m], 0, 0, 0);

            // next chunk (q+1) must have landed; exact drain at the tail
            if (q >= 106) { asm volatile("s_waitcnt vmcnt(0)" ::: "memory"); }
            else          { asm volatile("s_waitcnt vmcnt(2)" ::: "memory"); }
            __builtin_amdgcn_s_barrier();
            __builtin_amdgcn_sched_barrier(0);
            rb = rb == 2 ? 0 : rb + 1;
        }
    }

    const int pos_o = (i << 7) + j0 + px_l;
#pragma unroll
    for (int m = 0; m < 3; m++) {
        const int mt32 = mg * 3 + m;
#pragma unroll
        for (int reg = 0; reg < 16; reg++) {
            const int o = mt32 * 32 + (reg & 3) + ((reg >> 2) << 3) + (hi << 2);
            out[((size_t)(b * CC + o) << 14) + pos_o] = acc[m][reg] + bias[o];
        }
    }
}

// ---------------------------------------------------------------------------
extern "C" void kernel_launch(void* const* d_in, const int* in_sizes, int n_in,
                              void* d_out, int out_size, void* d_ws, size_t ws_size,
                              hipStream_t stream)
{
    const float* x_vq  = (const float*)d_in[0];
    const float* x_res = (const float*)d_in[1];
    const float* w_off = (const float*)d_in[2];
    const float* b_off = (const float*)d_in[3];
    const float* w_co  = (const float*)d_in[4];
    const float* b_co  = (const float*)d_in[5];
    const float* w_dcn = (const float*)d_in[6];
    const float* b_dcn = (const float*)d_in[7];
    float* out = (float*)d_out;

    char* ws = (char*)d_ws;
    unsigned short* xg = (unsigned short*)ws;                      // 25.17 MB
    const size_t xg_sz = (size_t)BB * 48 * HW * 8 * 2;
    unsigned short* fg = (unsigned short*)(ws + xg_sz);            // 12.58 MB
    const size_t fg_sz = (size_t)BB * 24 * HW * 8 * 2;
    float* offb = (float*)(ws + xg_sz + fg_sz);                    // 14.16 MB
    const size_t offb_sz = (size_t)BB * 108 * HW * 4;
    short* wA1 = (short*)(ws + xg_sz + fg_sz + offb_sz);           // 216*4096
    short* wA2 = wA1 + (size_t)216 * 4096;                         // 108*4096
    short* wA3 = wA2 + (size_t)108 * 4096;                         // 108*4096

    to_grp_k<<<dim3(BB * 48 * HW / 256), 256, 0, stream>>>(x_vq, x_res, xg);

    // packing. conv: k = c16*144 + tap*16 + cl -> w[o][c16*16+cl][tap]
    pack_w_k<<<(216 * 512 + 255) / 256, 256, 0, stream>>>(
        w_off, wA1, 192, 3456, 144, 144, 16, 1, 9, 216 * 512);
    pack_w_k<<<(108 * 512 + 255) / 256, 256, 0, stream>>>(
        w_co, wA2, 108, 1728, 144, 144, 16, 1, 9, 108 * 512);
    // dcn (c16-outer order): k = c16*144 + kt*16 + cl -> w[o][c16*16+cl][kt]
    pack_w_k<<<(108 * 512 + 255) / 256, 256, 0, stream>>>(
        w_dcn, wA3, 192, 1728, 144, 144, 16, 1, 9, 108 * 512);

    // conv1: xg [48 grp] -> fg [24 grp bf16]
    conv_g_k<3, 24, true><<<dim3(HH, BB), 512, 0, stream>>>(xg, wA1, b_off, fg, 192);
    // conv2: fg [24 grp] -> offb [108 planar f32]
    conv_g_k<2, 12, false><<<dim3(HH, BB), 512, 0, stream>>>(fg, wA2, b_co, offb, 108);
    // fused deform-sample + einsum
    dcn_g_k<<<dim3(2, HH, BB), 256, 0, stream>>>(xg, offb, wA3, b_dcn, out);
}

// Round 7
// 227.399 us; speedup vs baseline: 2.0448x; 1.1093x over previous
//
#include <hip/hip_runtime.h>
#include <math.h>

#define HH 128
#define WW 128
#define HW 16384
#define BB 2
#define CC 192

typedef __attribute__((ext_vector_type(8)))  short short8;
typedef __attribute__((ext_vector_type(4)))  float f32x4;
typedef __attribute__((ext_vector_type(16))) float f32x16;

// f32 -> bf16 bits, round-to-nearest-even
static __device__ __forceinline__ short f2bf(float f) {
    unsigned u = __float_as_uint(f);
    unsigned r = (u + 0x7FFFu + ((u >> 16) & 1u)) >> 16;
    return (short)r;
}
static __device__ __forceinline__ float bf2f(short s) {
    return __uint_as_float(((unsigned)(unsigned short)s) << 16);
}

// async global->LDS, 16B per lane. lds dest: wave-uniform base + lane*16.
static __device__ __forceinline__ void gl_lds16(const short* gsrc, short* ldst) {
    __builtin_amdgcn_global_load_lds(
        (const __attribute__((address_space(1))) unsigned*)gsrc,
        (__attribute__((address_space(3))) unsigned*)ldst, 16, 0, 0);
}

// ---------------------------------------------------------------------------
// Grouped channels-last transpose: xg[b][cg(48)][pos][8ch] bf16.
// ---------------------------------------------------------------------------
__global__ __launch_bounds__(256) void to_grp_k(
    const float* __restrict__ xv, const float* __restrict__ xr,
    unsigned short* __restrict__ xg)
{
    const int idx = blockIdx.x * 256 + threadIdx.x;   // (b*48+cg)*HW + pos
    const int pos = idx & (HW - 1);
    const int cgb = idx >> 14;
    const int cg  = cgb % 48;
    const int b   = cgb / 48;
    short8 v;
#pragma unroll
    for (int r = 0; r < 8; r++) {
        const int c = cg * 8 + r;
        const float f = (c < 192)
            ? xv[((size_t)(b * 192 + c) << 14) + pos]
            : xr[((size_t)(b * 192 + (c - 192)) << 14) + pos];
        v[r] = f2bf(f);
    }
    *reinterpret_cast<short8*>(xg + (size_t)idx * 8) = v;
}

// ---------------------------------------------------------------------------
// Pack f32 weights into 32x32x16 A-frag chunks of 8 KB:
// wp[chunk*4096 + slot*512 + lane*8 + r], o = slot*32+(lane&31),
// k = chunk*16 + (lane>>5)*8 + r; src = w[o*so + (k/d1)*s1
//      + ((k%d1)/d2)*s2 + ((k%d1)%d2)*s3]. Zero-pad o >= Co.
// ---------------------------------------------------------------------------
__global__ void pack_w_k(const float* __restrict__ w, short* __restrict__ wp,
                         int Co, int so, int d1, int s1, int d2, int s2, int s3,
                         int total)
{
    const int idx = blockIdx.x * blockDim.x + threadIdx.x;
    if (idx >= total) return;
    const int lane  = idx & 63;
    const int slot  = (idx >> 6) & 7;
    const int chunk = idx >> 9;
    const int o     = slot * 32 + (lane & 31);
    const int k0    = chunk * 16 + ((lane >> 5) << 3);
    short8 v;
#pragma unroll
    for (int r = 0; r < 8; r++) {
        const int k = k0 + r;
        float f = 0.f;
        if (o < Co) {
            const int rem = k % d1;
            f = w[(size_t)o * so + (k / d1) * s1 + (rem / d2) * s2 + (rem % d2) * s3];
        }
        v[r] = f2bf(f);
    }
    *reinterpret_cast<short8*>(wp + (size_t)idx * 8) = v;
}

// ---------------------------------------------------------------------------
// 3x3 conv (pad 1), implicit GEMM, 32x32x16 MFMA, grouped-CL input.
// Block = 256 thr (4 waves: mg=wid>>1 m-group, nt=wid&1 px-half), 64 px per
// (b,i,j0); grid 512 -> 2 independent blocks/CU. B prefetched 2 chunks ahead
// (register rotation), A staged 3 ahead into 4 LDS buffers via
// global_load_lds; uniform vmcnt(3) (2 stage + 1 B per iter, clamped tail).
// ---------------------------------------------------------------------------
template<int MTW, int NC16, bool OUT_GRP>
__global__ __launch_bounds__(256, 2) void conv_g_k(
    const unsigned short* __restrict__ xg,
    const short* __restrict__ wA, const float* __restrict__ bias,
    void* __restrict__ outp, int Cout)
{
    __shared__ __align__(16) short Abuf[4][4096];

    const int t    = threadIdx.x;
    const int lane = t & 63;
    const int wid  = t >> 6;
    const int mg   = wid >> 1;
    const int nt   = wid & 1;
    // XCD swizzle: nwg = 2*HH*BB = 512
    const int lin  = (blockIdx.z * HH + blockIdx.y) * 2 + blockIdx.x;
    const int og_  = (lin & 7) * 64 + (lin >> 3);
    const int j0   = (og_ & 1) * 64;
    const int i    = (og_ >> 1) & (HH - 1);
    const int b    = og_ >> 8;
    const int px   = j0 + (nt << 5) + (lane & 31);
    const int hi   = lane >> 5;
    constexpr int NQ = NC16 * 9;

    const unsigned short* __restrict__ xgb = xg + (size_t)b * (NC16 * 2) * HW * 8;

    f32x16 acc[MTW];
#pragma unroll
    for (int m = 0; m < MTW; m++)
#pragma unroll
        for (int r = 0; r < 16; r++) acc[m][r] = 0.f;

    auto loadB = [&](int qq, short8& dst, bool& vm) {
        const int c16 = qq / 9;
        const int tap = qq - c16 * 9;
        const int iy  = i + tap / 3 - 1;
        const int jx  = px + tap % 3 - 1;
        vm = ((unsigned)iy < HH) && ((unsigned)jx < WW);
        const int iyc = min(max(iy, 0), HH - 1);
        const int jxc = min(max(jx, 0), WW - 1);
        dst = *reinterpret_cast<const short8*>(
            xgb + ((size_t)(c16 * 2 + hi) * HW + (iyc << 7) + jxc) * 8);
    };

    short8 bA, bB;
    bool mA = false, mB = false;

    // prologue queue: s0(2), s1(2), B0(1), s2(2), B1(1)
    gl_lds16(wA + (size_t)0 * 4096 + t * 8,         &Abuf[0][wid * 512]);
    gl_lds16(wA + (size_t)0 * 4096 + (t + 256) * 8, &Abuf[0][2048 + wid * 512]);
    gl_lds16(wA + (size_t)1 * 4096 + t * 8,         &Abuf[1][wid * 512]);
    gl_lds16(wA + (size_t)1 * 4096 + (t + 256) * 8, &Abuf[1][2048 + wid * 512]);
    loadB(0, bA, mA);
    gl_lds16(wA + (size_t)2 * 4096 + t * 8,         &Abuf[2][wid * 512]);
    gl_lds16(wA + (size_t)2 * 4096 + (t + 256) * 8, &Abuf[2][2048 + wid * 512]);
    loadB(1, bB, mB);

#define CSTEP(Q, BC, MC)                                                      \
    {                                                                         \
        asm volatile("s_waitcnt vmcnt(3)" ::: "memory");                      \
        __builtin_amdgcn_s_barrier();                                         \
        __builtin_amdgcn_sched_barrier(0);                                    \
        const int sc_ = min((Q) + 3, NQ - 1);                                 \
        gl_lds16(wA + (size_t)sc_ * 4096 + t * 8,                             \
                 &Abuf[((Q) + 3) & 3][wid * 512]);                            \
        gl_lds16(wA + (size_t)sc_ * 4096 + (t + 256) * 8,                     \
                 &Abuf[((Q) + 3) & 3][2048 + wid * 512]);                     \
        short8 bF = BC;                                                       \
        if (!MC) {                                                            \
            _Pragma("unroll")                                                 \
            for (int r = 0; r < 8; r++) bF[r] = 0;                            \
        }                                                                     \
        loadB(min((Q) + 2, NQ - 1), BC, MC);                                  \
        const short* ab_ = &Abuf[(Q) & 3][(mg * MTW) * 512 + lane * 8];       \
        short8 aF[MTW];                                                       \
        _Pragma("unroll")                                                     \
        for (int m = 0; m < MTW; m++)                                         \
            aF[m] = *reinterpret_cast<const short8*>(ab_ + m * 512);          \
        _Pragma("unroll")                                                     \
        for (int m = 0; m < MTW; m++)                                         \
            acc[m] = __builtin_amdgcn_mfma_f32_32x32x16_bf16(aF[m], bF, acc[m], 0, 0, 0); \
    }

    for (int q = 0; q < NQ; q += 2) {
        CSTEP(q, bA, mA);
        CSTEP(q + 1, bB, mB);
    }
#undef CSTEP

    // store. C/D: col = lane&31 -> px ; row = (reg&3)+8*(reg>>2)+4*hi -> o.
    const int pos_o = (i << 7) + px;
    if constexpr (OUT_GRP) {
        unsigned short* fg = (unsigned short*)outp;
#pragma unroll
        for (int m = 0; m < MTW; m++) {
            const int mt32 = mg * MTW + m;
#pragma unroll
            for (int g = 0; g < 4; g++) {
                const int ob = mt32 * 32 + 8 * g + 4 * hi;
                const unsigned s0 = (unsigned short)f2bf(acc[m][4 * g + 0] + bias[ob + 0]);
                const unsigned s1 = (unsigned short)f2bf(acc[m][4 * g + 1] + bias[ob + 1]);
                const unsigned s2 = (unsigned short)f2bf(acc[m][4 * g + 2] + bias[ob + 2]);
                const unsigned s3 = (unsigned short)f2bf(acc[m][4 * g + 3] + bias[ob + 3]);
                const int cg = mt32 * 4 + g;
                *reinterpret_cast<uint2*>(
                    fg + ((size_t)(b * (Cout >> 3) + cg) * HW + pos_o) * 8 + 4 * hi) =
                    make_uint2(s0 | (s1 << 16), s2 | (s3 << 16));
            }
        }
    } else {
        float* of = (float*)outp;
#pragma unroll
        for (int m = 0; m < MTW; m++) {
            const int mt32 = mg * MTW + m;
#pragma unroll
            for (int reg = 0; reg < 16; reg++) {
                const int o = mt32 * 32 + (reg & 3) + ((reg >> 2) << 3) + (hi << 2);
                if (o < Cout)
                    of[((size_t)(b * Cout + o) << 14) + pos_o] = acc[m][reg] + bias[o];
            }
        }
    }
}

// ---------------------------------------------------------------------------
// Fused deform-sample + einsum, 32x32x16 MFMA, grouped-CL x, streamed A.
// Block = 256 thr (4 waves), 192 o x 64 px per (b,i,j0); c16-outer chunk
// order (x read ~once). Corner gathers double-buffered in REGISTERS and
// issued one chunk ahead (~1000 cyc cover); uniform per-iter issue
// (4 G + 2 stage, clamped tail) -> exact vmcnt(6) everywhere.
// ---------------------------------------------------------------------------
__global__ __launch_bounds__(256, 2) void dcn_g_k(
    const unsigned short* __restrict__ xg, const float* __restrict__ off,
    const short* __restrict__ wA, const float* __restrict__ bias,
    float* __restrict__ out)
{
    __shared__ __align__(16) f32x4 eW[2304];      // 36 KB
    __shared__ __align__(8)  uint2 eO[2304];      // 18 KB
    __shared__ __align__(16) short Abuf[3][4096]; // 24 KB

    const int t    = threadIdx.x;
    const int lane = t & 63;
    const int wid  = t >> 6;
    const int mg   = wid >> 1;
    const int nt   = wid & 1;
    // XCD swizzle: nwg = 2*HH*BB = 512
    const int lin  = (blockIdx.z * HH + blockIdx.y) * 2 + blockIdx.x;
    const int og_  = (lin & 7) * 64 + (lin >> 3);
    const int j0   = (og_ & 1) * 64;
    const int i    = (og_ >> 1) & (HH - 1);
    const int b    = og_ >> 8;

    // ---- A1: bilinear entries (identical math to verified rounds 2-6) ----
    for (int e = t; e < 2304; e += 256) {
        const int p  = e & 63;
        const int gk = e >> 6;               // g*9 + kt
        const int kt = gk % 9;
        const int j  = j0 + p;
        const size_t sp = (size_t)b * 108 * HW + (size_t)gk * HW + (i << 7) + j;
        const float dy = off[sp];
        const float dx = off[sp + (size_t)36 * HW];
        const float mv = off[sp + (size_t)72 * HW];
        const float m  = 1.f / (1.f + expf(-mv));
        const float py = (float)(i + kt / 3 - 1) + dy;
        const float px = (float)(j + kt % 3 - 1) + dx;
        const float y0f = floorf(py), x0f = floorf(px);
        const float ly = py - y0f, lx = px - x0f;
        const int y0 = (int)y0f, x0 = (int)x0f;
        const float vy0 = (y0 >= 0 && y0 < HH) ? 1.f : 0.f;
        const float vy1 = (y0 + 1 >= 0 && y0 + 1 < HH) ? 1.f : 0.f;
        const float vx0 = (x0 >= 0 && x0 < WW) ? 1.f : 0.f;
        const float vx1 = (x0 + 1 >= 0 && x0 + 1 < WW) ? 1.f : 0.f;
        f32x4 w4;
        w4[0] = (1.f - ly) * (1.f - lx) * m * vy0 * vx0;
        w4[1] = (1.f - ly) * lx         * m * vy0 * vx1;
        w4[2] = ly         * (1.f - lx) * m * vy1 * vx0;
        w4[3] = ly         * lx         * m * vy1 * vx1;
        const int yc0 = min(max(y0, 0), HH - 1);
        const int yc1 = min(max(y0 + 1, 0), HH - 1);
        const int xc0 = min(max(x0, 0), WW - 1);
        const int xc1 = min(max(x0 + 1, 0), WW - 1);
        eW[e] = w4;
        eO[e] = make_uint2((unsigned)((yc0 << 7) + xc0) | ((unsigned)((yc0 << 7) + xc1) << 16),
                           (unsigned)((yc1 << 7) + xc0) | ((unsigned)((yc1 << 7) + xc1) << 16));
    }
    __syncthreads();

    const int px_l = (nt << 5) + (lane & 31);
    const int hi   = lane >> 5;
    const unsigned short* __restrict__ xgb = xg + (size_t)b * 48 * HW * 8;

    f32x16 acc[3];
#pragma unroll
    for (int m = 0; m < 3; m++)
#pragma unroll
        for (int r = 0; r < 16; r++) acc[m][r] = 0.f;

#define GISSUE(QQ, N0, N1, N2, N3, WN)                                        \
    {                                                                         \
        const int qn_   = min((QQ), 107);                                     \
        const int c16n_ = qn_ / 9;                                            \
        const int ktn_  = qn_ - 9 * c16n_;                                    \
        const int e_    = ((c16n_ / 3) * 9 + ktn_) * 64 + px_l;               \
        const uint2 o_  = eO[e_];                                             \
        WN = eW[e_];                                                          \
        const unsigned short* base_ = xgb + (size_t)(c16n_ * 2 + hi) * (HW * 8); \
        N0 = *reinterpret_cast<const short8*>(base_ + (size_t)(o_.x & 0xFFFFu) * 8); \
        N1 = *reinterpret_cast<const short8*>(base_ + (size_t)(o_.x >> 16) * 8);     \
        N2 = *reinterpret_cast<const short8*>(base_ + (size_t)(o_.y & 0xFFFFu) * 8); \
        N3 = *reinterpret_cast<const short8*>(base_ + (size_t)(o_.y >> 16) * 8);     \
    }

    short8 Ga0, Ga1, Ga2, Ga3, Gb0, Gb1, Gb2, Gb3;
    f32x4 wGa, wGb;
    int rb = 0;

    // prologue queue: s0(2), G0(4), s1(2)
    gl_lds16(wA + (size_t)0 * 4096 + t * 8,         &Abuf[0][wid * 512]);
    gl_lds16(wA + (size_t)0 * 4096 + (t + 256) * 8, &Abuf[0][2048 + wid * 512]);
    GISSUE(0, Ga0, Ga1, Ga2, Ga3, wGa);
    gl_lds16(wA + (size_t)1 * 4096 + t * 8,         &Abuf[1][wid * 512]);
    gl_lds16(wA + (size_t)1 * 4096 + (t + 256) * 8, &Abuf[1][2048 + wid * 512]);

#define DSTEP(Q, C0, C1, C2, C3, WC, N0, N1, N2, N3, WN)                      \
    {                                                                         \
        GISSUE((Q) + 1, N0, N1, N2, N3, WN);                                  \
        asm volatile("s_waitcnt vmcnt(6)" ::: "memory");                      \
        __builtin_amdgcn_s_barrier();                                         \
        __builtin_amdgcn_sched_barrier(0);                                    \
        const int sc_ = min((Q) + 2, 107);                                    \
        const int sb_ = rb >= 1 ? rb - 1 : 2;  /* (rb+2)%3 */                 \
        gl_lds16(wA + (size_t)sc_ * 4096 + t * 8, &Abuf[sb_][wid * 512]);     \
        gl_lds16(wA + (size_t)sc_ * 4096 + (t + 256) * 8,                     \
                 &Abuf[sb_][2048 + wid * 512]);                               \
        short8 bF;                                                            \
        _Pragma("unroll")                                                     \
        for (int r = 0; r < 8; r++) {                                         \
            const float v = WC[0] * bf2f(C0[r]) + WC[1] * bf2f(C1[r])         \
                          + WC[2] * bf2f(C2[r]) + WC[3] * bf2f(C3[r]);        \
            bF[r] = f2bf(v);                                                  \
        }                                                                     \
        short8 aF[3];                                                         \
        _Pragma("unroll")                                                     \
        for (int m = 0; m < 3; m++)                                           \
            aF[m] = *reinterpret_cast<const short8*>(                         \
                &Abuf[rb][(mg * 3 + m) * 512 + lane * 8]);                    \
        _Pragma("unroll")                                                     \
        for (int m = 0; m < 3; m++)                                           \
            acc[m] = __builtin_amdgcn_mfma_f32_32x32x16_bf16(aF[m], bF, acc[m], 0, 0, 0); \
        rb = rb == 2 ? 0 : rb + 1;                                            \
    }

    for (int q = 0; q < 108; q += 2) {
        DSTEP(q,     Ga0, Ga1, Ga2, Ga3, wGa, Gb0, Gb1, Gb2, Gb3, wGb);
        DSTEP(q + 1, Gb0, Gb1, Gb2, Gb3, wGb, Ga0, Ga1, Ga2, Ga3, wGa);
    }
#undef DSTEP
#undef GISSUE

    const int pos_o = (i << 7) + j0 + px_l;
#pragma unroll
    for (int m = 0; m < 3; m++) {
        const int mt32 = mg * 3 + m;
#pragma unroll
        for (int reg = 0; reg < 16; reg++) {
            const int o = mt32 * 32 + (reg & 3) + ((reg >> 2) << 3) + (hi << 2);
            out[((size_t)(b * CC + o) << 14) + pos_o] = acc[m][reg] + bias[o];
        }
    }
}

// ---------------------------------------------------------------------------
extern "C" void kernel_launch(void* const* d_in, const int* in_sizes, int n_in,
                              void* d_out, int out_size, void* d_ws, size_t ws_size,
                              hipStream_t stream)
{
    const float* x_vq  = (const float*)d_in[0];
    const float* x_res = (const float*)d_in[1];
    const float* w_off = (const float*)d_in[2];
    const float* b_off = (const float*)d_in[3];
    const float* w_co  = (const float*)d_in[4];
    const float* b_co  = (const float*)d_in[5];
    const float* w_dcn = (const float*)d_in[6];
    const float* b_dcn = (const float*)d_in[7];
    float* out = (float*)d_out;

    char* ws = (char*)d_ws;
    unsigned short* xg = (unsigned short*)ws;                      // 25.17 MB
    const size_t xg_sz = (size_t)BB * 48 * HW * 8 * 2;
    unsigned short* fg = (unsigned short*)(ws + xg_sz);            // 12.58 MB
    const size_t fg_sz = (size_t)BB * 24 * HW * 8 * 2;
    float* offb = (float*)(ws + xg_sz + fg_sz);                    // 14.16 MB
    const size_t offb_sz = (size_t)BB * 108 * HW * 4;
    short* wA1 = (short*)(ws + xg_sz + fg_sz + offb_sz);           // 216*4096
    short* wA2 = wA1 + (size_t)216 * 4096;                         // 108*4096
    short* wA3 = wA2 + (size_t)108 * 4096;                         // 108*4096

    to_grp_k<<<dim3(BB * 48 * HW / 256), 256, 0, stream>>>(x_vq, x_res, xg);

    // packing. conv: k = c16*144 + tap*16 + cl -> w[o][c16*16+cl][tap]
    pack_w_k<<<(216 * 512 + 255) / 256, 256, 0, stream>>>(
        w_off, wA1, 192, 3456, 144, 144, 16, 1, 9, 216 * 512);
    pack_w_k<<<(108 * 512 + 255) / 256, 256, 0, stream>>>(
        w_co, wA2, 108, 1728, 144, 144, 16, 1, 9, 108 * 512);
    // dcn (c16-outer order): k = c16*144 + kt*16 + cl -> w[o][c16*16+cl][kt]
    pack_w_k<<<(108 * 512 + 255) / 256, 256, 0, stream>>>(
        w_dcn, wA3, 192, 1728, 144, 144, 16, 1, 9, 108 * 512);

    dim3 grid(2, HH, BB);
    // conv1: xg [48 grp] -> fg [24 grp bf16]
    conv_g_k<3, 24, true><<<grid, 256, 0, stream>>>(xg, wA1, b_off, fg, 192);
    // conv2: fg [24 grp] -> offb [108 planar f32]
    conv_g_k<2, 12, false><<<grid, 256, 0, stream>>>(fg, wA2, b_co, offb, 108);
    // fused deform-sample + einsum
    dcn_g_k<<<grid, 256, 0, stream>>>(xg, offb, wA3, b_dcn, out);
}

// Round 8
// 197.190 us; speedup vs baseline: 2.3580x; 1.1532x over previous
//
#include <hip/hip_runtime.h>
#include <math.h>

#define HH 128
#define WW 128
#define HW 16384
#define BB 2
#define CC 192

typedef __attribute__((ext_vector_type(8)))  short short8;
typedef __attribute__((ext_vector_type(4)))  float f32x4;
typedef __attribute__((ext_vector_type(16))) float f32x16;

// f32 -> bf16 bits, round-to-nearest-even
static __device__ __forceinline__ short f2bf(float f) {
    unsigned u = __float_as_uint(f);
    unsigned r = (u + 0x7FFFu + ((u >> 16) & 1u)) >> 16;
    return (short)r;
}
static __device__ __forceinline__ float bf2f(short s) {
    return __uint_as_float(((unsigned)(unsigned short)s) << 16);
}

// async global->LDS, 16B per lane. lds dest: wave-uniform base + lane*16.
static __device__ __forceinline__ void gl_lds16(const short* gsrc, short* ldst) {
    __builtin_amdgcn_global_load_lds(
        (const __attribute__((address_space(1))) unsigned*)gsrc,
        (__attribute__((address_space(3))) unsigned*)ldst, 16, 0, 0);
}

// ---------------------------------------------------------------------------
// Grouped channels-last transpose: xg[b][cg(48)][pos][8ch] bf16.
// ---------------------------------------------------------------------------
__global__ __launch_bounds__(256) void to_grp_k(
    const float* __restrict__ xv, const float* __restrict__ xr,
    unsigned short* __restrict__ xg)
{
    const int idx = blockIdx.x * 256 + threadIdx.x;   // (b*48+cg)*HW + pos
    const int pos = idx & (HW - 1);
    const int cgb = idx >> 14;
    const int cg  = cgb % 48;
    const int b   = cgb / 48;
    short8 v;
#pragma unroll
    for (int r = 0; r < 8; r++) {
        const int c = cg * 8 + r;
        const float f = (c < 192)
            ? xv[((size_t)(b * 192 + c) << 14) + pos]
            : xr[((size_t)(b * 192 + (c - 192)) << 14) + pos];
        v[r] = f2bf(f);
    }
    *reinterpret_cast<short8*>(xg + (size_t)idx * 8) = v;
}

// ---------------------------------------------------------------------------
// Pack f32 weights into 32x32x16 A-frag chunks of 8 KB:
// wp[chunk*4096 + slot*512 + lane*8 + r], o = slot*32+(lane&31),
// k = chunk*16 + (lane>>5)*8 + r; src = w[o*so + (k/d1)*s1
//      + ((k%d1)/d2)*s2 + ((k%d1)%d2)*s3]. Zero-pad o >= Co.
// ---------------------------------------------------------------------------
__global__ void pack_w_k(const float* __restrict__ w, short* __restrict__ wp,
                         int Co, int so, int d1, int s1, int d2, int s2, int s3,
                         int total)
{
    const int idx = blockIdx.x * blockDim.x + threadIdx.x;
    if (idx >= total) return;
    const int lane  = idx & 63;
    const int slot  = (idx >> 6) & 7;
    const int chunk = idx >> 9;
    const int o     = slot * 32 + (lane & 31);
    const int k0    = chunk * 16 + ((lane >> 5) << 3);
    short8 v;
#pragma unroll
    for (int r = 0; r < 8; r++) {
        const int k = k0 + r;
        float f = 0.f;
        if (o < Co) {
            const int rem = k % d1;
            f = w[(size_t)o * so + (k / d1) * s1 + (rem / d2) * s2 + (rem % d2) * s3];
        }
        v[r] = f2bf(f);
    }
    *reinterpret_cast<short8*>(wp + (size_t)idx * 8) = v;
}

// ---------------------------------------------------------------------------
// 3x3 conv (pad 1), implicit GEMM, 32x32x16 MFMA, grouped-CL input.
// Block = 256 thr (4 waves: mg=wid>>1, nt=wid&1), 64 px per (b,i,j0).
// TWO chunks per barrier: paired LDS buffers Pbuf[3][2][4096], 6-deep B reg
// rotation. Queue invariant at each vmcnt: [B(p+1)2, S(p+1)4, B(p+2)2] = 8
// outstanding -> vmcnt(8) drains exactly {S(p), B(p)}.
// ---------------------------------------------------------------------------
template<int MTW, int NC16, bool OUT_GRP>
__global__ __launch_bounds__(256, 2) void conv_g_k(
    const unsigned short* __restrict__ xg,
    const short* __restrict__ wA, const float* __restrict__ bias,
    void* __restrict__ outp, int Cout)
{
    __shared__ __align__(16) short Pbuf[3][2][4096];

    const int t    = threadIdx.x;
    const int lane = t & 63;
    const int wid  = t >> 6;
    const int mg   = wid >> 1;
    const int nt   = wid & 1;
    // XCD swizzle: nwg = 2*HH*BB = 512
    const int lin  = (blockIdx.z * HH + blockIdx.y) * 2 + blockIdx.x;
    const int og_  = (lin & 7) * 64 + (lin >> 3);
    const int j0   = (og_ & 1) * 64;
    const int i    = (og_ >> 1) & (HH - 1);
    const int b    = og_ >> 8;
    const int px   = j0 + (nt << 5) + (lane & 31);
    const int hi   = lane >> 5;
    constexpr int NQ = NC16 * 9;
    constexpr int NP = NQ / 2;   // pairs (divisible by 3)

    const unsigned short* __restrict__ xgb = xg + (size_t)b * (NC16 * 2) * HW * 8;

    f32x16 acc[MTW];
#pragma unroll
    for (int m = 0; m < MTW; m++)
#pragma unroll
        for (int r = 0; r < 16; r++) acc[m][r] = 0.f;

    auto loadB = [&](int qq, short8& dst, bool& vm) {
        const int c16 = qq / 9;
        const int tap = qq - c16 * 9;
        const int iy  = i + tap / 3 - 1;
        const int jx  = px + tap % 3 - 1;
        vm = ((unsigned)iy < HH) && ((unsigned)jx < WW);
        const int iyc = min(max(iy, 0), HH - 1);
        const int jxc = min(max(jx, 0), WW - 1);
        dst = *reinterpret_cast<const short8*>(
            xgb + ((size_t)(c16 * 2 + hi) * HW + (iyc << 7) + jxc) * 8);
    };
    auto stage2 = [&](int chunk, int pb, int sl) {
        gl_lds16(wA + (size_t)chunk * 4096 + t * 8,         &Pbuf[pb][sl][wid * 512]);
        gl_lds16(wA + (size_t)chunk * 4096 + (t + 256) * 8, &Pbuf[pb][sl][2048 + wid * 512]);
    };

    short8 B0, B1, B2, B3, B4, B5;
    bool M0, M1, M2, M3, M4, M5;

    // prologue order (queue invariant): S(pair0)4, B(pair0)2, S(pair1)4, B(pair1)2
    stage2(0, 0, 0); stage2(1, 0, 1);
    loadB(0, B0, M0); loadB(1, B1, M1);
    stage2(2, 1, 0); stage2(3, 1, 1);
    loadB(2, B2, M2); loadB(3, B3, M3);

#define CCHUNK(IBUF, SL, BC, MC)                                              \
    {                                                                         \
        short8 bF = BC;                                                       \
        if (!MC) {                                                            \
            _Pragma("unroll")                                                 \
            for (int r = 0; r < 8; r++) bF[r] = 0;                            \
        }                                                                     \
        const short* ab_ = &Pbuf[IBUF][SL][(mg * MTW) * 512 + lane * 8];      \
        short8 aF[MTW];                                                       \
        _Pragma("unroll")                                                     \
        for (int m = 0; m < MTW; m++)                                         \
            aF[m] = *reinterpret_cast<const short8*>(ab_ + m * 512);          \
        _Pragma("unroll")                                                     \
        for (int m = 0; m < MTW; m++)                                         \
            acc[m] = __builtin_amdgcn_mfma_f32_32x32x16_bf16(aF[m], bF, acc[m], 0, 0, 0); \
    }

#define PSTEP(P, IBUF, SBUF, Bc0, Mc0, Bc1, Mc1, Bn0, Mn0, Bn1, Mn1)          \
    {                                                                         \
        loadB(min(2 * ((P) + 2),     NQ - 1), Bn0, Mn0);                      \
        loadB(min(2 * ((P) + 2) + 1, NQ - 1), Bn1, Mn1);                      \
        asm volatile("s_waitcnt vmcnt(8)" ::: "memory");                      \
        __builtin_amdgcn_s_barrier();                                         \
        __builtin_amdgcn_sched_barrier(0);                                    \
        const int sc0_ = min(2 * ((P) + 2),     NQ - 1);                      \
        const int sc1_ = min(2 * ((P) + 2) + 1, NQ - 1);                      \
        stage2(sc0_, SBUF, 0); stage2(sc1_, SBUF, 1);                         \
        CCHUNK(IBUF, 0, Bc0, Mc0);                                            \
        CCHUNK(IBUF, 1, Bc1, Mc1);                                            \
    }

    for (int pp = 0; pp < NP; pp += 3) {
        PSTEP(pp + 0, 0, 2, B0, M0, B1, M1, B4, M4, B5, M5);
        PSTEP(pp + 1, 1, 0, B2, M2, B3, M3, B0, M0, B1, M1);
        PSTEP(pp + 2, 2, 1, B4, M4, B5, M5, B2, M2, B3, M3);
    }
#undef PSTEP
#undef CCHUNK

    // store. C/D: col = lane&31 -> px ; row = (reg&3)+8*(reg>>2)+4*hi -> o.
    const int pos_o = (i << 7) + px;
    if constexpr (OUT_GRP) {
        unsigned short* fg = (unsigned short*)outp;
#pragma unroll
        for (int m = 0; m < MTW; m++) {
            const int mt32 = mg * MTW + m;
#pragma unroll
            for (int g = 0; g < 4; g++) {
                const int ob = mt32 * 32 + 8 * g + 4 * hi;
                const unsigned s0 = (unsigned short)f2bf(acc[m][4 * g + 0] + bias[ob + 0]);
                const unsigned s1 = (unsigned short)f2bf(acc[m][4 * g + 1] + bias[ob + 1]);
                const unsigned s2 = (unsigned short)f2bf(acc[m][4 * g + 2] + bias[ob + 2]);
                const unsigned s3 = (unsigned short)f2bf(acc[m][4 * g + 3] + bias[ob + 3]);
                const int cg = mt32 * 4 + g;
                *reinterpret_cast<uint2*>(
                    fg + ((size_t)(b * (Cout >> 3) + cg) * HW + pos_o) * 8 + 4 * hi) =
                    make_uint2(s0 | (s1 << 16), s2 | (s3 << 16));
            }
        }
    } else {
        float* of = (float*)outp;
#pragma unroll
        for (int m = 0; m < MTW; m++) {
            const int mt32 = mg * MTW + m;
#pragma unroll
            for (int reg = 0; reg < 16; reg++) {
                const int o = mt32 * 32 + (reg & 3) + ((reg >> 2) << 3) + (hi << 2);
                if (o < Cout)
                    of[((size_t)(b * Cout + o) << 14) + pos_o] = acc[m][reg] + bias[o];
            }
        }
    }
}

// ---------------------------------------------------------------------------
// Fused deform-sample + einsum, 32x32x16 MFMA, BARRIER-FREE K-loop.
// Block = 128 thr (2 waves, mg = wid), 32 px x 192 out-ch per block;
// grid 1024 -> 4 blocks/CU, 8 free-running waves/CU. A-fragments loaded
// global->register (coalesced b128, wave-private, ping-pong 1 chunk ahead);
// corner gathers likewise. Uniform per-iter issue 3A+4G -> vmcnt(7).
// LDS holds only the A1 bilinear entries (27.6 KB).
// ---------------------------------------------------------------------------
__global__ __launch_bounds__(128, 2) void dcn_g_k(
    const unsigned short* __restrict__ xg, const float* __restrict__ off,
    const short* __restrict__ wA, const float* __restrict__ bias,
    float* __restrict__ out)
{
    __shared__ __align__(16) f32x4 eW[1152];   // 18.4 KB (36 gk x 32 px)
    __shared__ __align__(8)  uint2 eO[1152];   //  9.2 KB

    const int t    = threadIdx.x;
    const int lane = t & 63;
    const int mg   = t >> 6;     // wave id = m-half
    // XCD swizzle: nwg = 4*HH*BB = 1024
    const int lin  = (blockIdx.z * HH + blockIdx.y) * 4 + blockIdx.x;
    const int og_  = (lin & 7) * 128 + (lin >> 3);
    const int jt   = og_ & 3;
    const int i    = (og_ >> 2) & (HH - 1);
    const int b    = og_ >> 9;
    const int j0   = jt * 32;

    // ---- A1: bilinear entries (identical math to verified rounds 2-7) ----
    for (int e = t; e < 1152; e += 128) {
        const int p  = e & 31;
        const int gk = e >> 5;               // g*9 + kt
        const int kt = gk % 9;
        const int j  = j0 + p;
        const size_t sp = (size_t)b * 108 * HW + (size_t)gk * HW + (i << 7) + j;
        const float dy = off[sp];
        const float dx = off[sp + (size_t)36 * HW];
        const float mv = off[sp + (size_t)72 * HW];
        const float m  = 1.f / (1.f + expf(-mv));
        const float py = (float)(i + kt / 3 - 1) + dy;
        const float px = (float)(j + kt % 3 - 1) + dx;
        const float y0f = floorf(py), x0f = floorf(px);
        const float ly = py - y0f, lx = px - x0f;
        const int y0 = (int)y0f, x0 = (int)x0f;
        const float vy0 = (y0 >= 0 && y0 < HH) ? 1.f : 0.f;
        const float vy1 = (y0 + 1 >= 0 && y0 + 1 < HH) ? 1.f : 0.f;
        const float vx0 = (x0 >= 0 && x0 < WW) ? 1.f : 0.f;
        const float vx1 = (x0 + 1 >= 0 && x0 + 1 < WW) ? 1.f : 0.f;
        f32x4 w4;
        w4[0] = (1.f - ly) * (1.f - lx) * m * vy0 * vx0;
        w4[1] = (1.f - ly) * lx         * m * vy0 * vx1;
        w4[2] = ly         * (1.f - lx) * m * vy1 * vx0;
        w4[3] = ly         * lx         * m * vy1 * vx1;
        const int yc0 = min(max(y0, 0), HH - 1);
        const int yc1 = min(max(y0 + 1, 0), HH - 1);
        const int xc0 = min(max(x0, 0), WW - 1);
        const int xc1 = min(max(x0 + 1, 0), WW - 1);
        eW[e] = w4;
        eO[e] = make_uint2((unsigned)((yc0 << 7) + xc0) | ((unsigned)((yc0 << 7) + xc1) << 16),
                           (unsigned)((yc1 << 7) + xc0) | ((unsigned)((yc1 << 7) + xc1) << 16));
    }
    __syncthreads();

    const int px_l = lane & 31;
    const int hi   = lane >> 5;
    const unsigned short* __restrict__ xgb = xg + (size_t)b * 48 * HW * 8;

    f32x16 acc[3];
#pragma unroll
    for (int m = 0; m < 3; m++)
#pragma unroll
        for (int r = 0; r < 16; r++) acc[m][r] = 0.f;

#define AISSUE(QQ, A0, A1, A2)                                                \
    {                                                                         \
        const int qn_ = min((QQ), 107);                                       \
        const short* ap_ = wA + (size_t)qn_ * 4096 + (mg * 3) * 512 + lane * 8; \
        A0 = *reinterpret_cast<const short8*>(ap_);                           \
        A1 = *reinterpret_cast<const short8*>(ap_ + 512);                     \
        A2 = *reinterpret_cast<const short8*>(ap_ + 1024);                    \
    }

#define GISSUE(QQ, N0, N1, N2, N3, WN)                                        \
    {                                                                         \
        const int qn_   = min((QQ), 107);                                     \
        const int c16n_ = qn_ / 9;                                            \
        const int ktn_  = qn_ - 9 * c16n_;                                    \
        const int e_    = ((c16n_ / 3) * 9 + ktn_) * 32 + px_l;               \
        const uint2 o_  = eO[e_];                                             \
        WN = eW[e_];                                                          \
        const unsigned short* base_ = xgb + (size_t)(c16n_ * 2 + hi) * (HW * 8); \
        N0 = *reinterpret_cast<const short8*>(base_ + (size_t)(o_.x & 0xFFFFu) * 8); \
        N1 = *reinterpret_cast<const short8*>(base_ + (size_t)(o_.x >> 16) * 8);     \
        N2 = *reinterpret_cast<const short8*>(base_ + (size_t)(o_.y & 0xFFFFu) * 8); \
        N3 = *reinterpret_cast<const short8*>(base_ + (size_t)(o_.y >> 16) * 8);     \
    }

#define DSTEP(Q, Ac0, Ac1, Ac2, C0, C1, C2, C3, WC, An0, An1, An2, N0, N1, N2, N3, WN) \
    {                                                                         \
        AISSUE((Q) + 1, An0, An1, An2);                                       \
        GISSUE((Q) + 1, N0, N1, N2, N3, WN);                                  \
        asm volatile("s_waitcnt vmcnt(7)" ::: "memory");                      \
        short8 bF;                                                            \
        _Pragma("unroll")                                                     \
        for (int r = 0; r < 8; r++) {                                         \
            const float v = WC[0] * bf2f(C0[r]) + WC[1] * bf2f(C1[r])         \
                          + WC[2] * bf2f(C2[r]) + WC[3] * bf2f(C3[r]);        \
            bF[r] = f2bf(v);                                                  \
        }                                                                     \
        acc[0] = __builtin_amdgcn_mfma_f32_32x32x16_bf16(Ac0, bF, acc[0], 0, 0, 0); \
        acc[1] = __builtin_amdgcn_mfma_f32_32x32x16_bf16(Ac1, bF, acc[1], 0, 0, 0); \
        acc[2] = __builtin_amdgcn_mfma_f32_32x32x16_bf16(Ac2, bF, acc[2], 0, 0, 0); \
    }

    short8 Aa0, Aa1, Aa2, Ab0, Ab1, Ab2;
    short8 Ga0, Ga1, Ga2, Ga3, Gb0, Gb1, Gb2, Gb3;
    f32x4 wGa, wGb;

    AISSUE(0, Aa0, Aa1, Aa2);
    GISSUE(0, Ga0, Ga1, Ga2, Ga3, wGa);

    for (int q = 0; q < 108; q += 2) {
        DSTEP(q,     Aa0, Aa1, Aa2, Ga0, Ga1, Ga2, Ga3, wGa,
                     Ab0, Ab1, Ab2, Gb0, Gb1, Gb2, Gb3, wGb);
        DSTEP(q + 1, Ab0, Ab1, Ab2, Gb0, Gb1, Gb2, Gb3, wGb,
                     Aa0, Aa1, Aa2, Ga0, Ga1, Ga2, Ga3, wGa);
    }
#undef DSTEP
#undef GISSUE
#undef AISSUE

    const int pos_o = (i << 7) + j0 + px_l;
#pragma unroll
    for (int m = 0; m < 3; m++) {
        const int mt32 = mg * 3 + m;
#pragma unroll
        for (int reg = 0; reg < 16; reg++) {
            const int o = mt32 * 32 + (reg & 3) + ((reg >> 2) << 3) + (hi << 2);
            out[((size_t)(b * CC + o) << 14) + pos_o] = acc[m][reg] + bias[o];
        }
    }
}

// ---------------------------------------------------------------------------
extern "C" void kernel_launch(void* const* d_in, const int* in_sizes, int n_in,
                              void* d_out, int out_size, void* d_ws, size_t ws_size,
                              hipStream_t stream)
{
    const float* x_vq  = (const float*)d_in[0];
    const float* x_res = (const float*)d_in[1];
    const float* w_off = (const float*)d_in[2];
    const float* b_off = (const float*)d_in[3];
    const float* w_co  = (const float*)d_in[4];
    const float* b_co  = (const float*)d_in[5];
    const float* w_dcn = (const float*)d_in[6];
    const float* b_dcn = (const float*)d_in[7];
    float* out = (float*)d_out;

    char* ws = (char*)d_ws;
    unsigned short* xg = (unsigned short*)ws;                      // 25.17 MB
    const size_t xg_sz = (size_t)BB * 48 * HW * 8 * 2;
    unsigned short* fg = (unsigned short*)(ws + xg_sz);            // 12.58 MB
    const size_t fg_sz = (size_t)BB * 24 * HW * 8 * 2;
    float* offb = (float*)(ws + xg_sz + fg_sz);                    // 14.16 MB
    const size_t offb_sz = (size_t)BB * 108 * HW * 4;
    short* wA1 = (short*)(ws + xg_sz + fg_sz + offb_sz);           // 216*4096
    short* wA2 = wA1 + (size_t)216 * 4096;                         // 108*4096
    short* wA3 = wA2 + (size_t)108 * 4096;                         // 108*4096

    to_grp_k<<<dim3(BB * 48 * HW / 256), 256, 0, stream>>>(x_vq, x_res, xg);

    // packing. conv: k = c16*144 + tap*16 + cl -> w[o][c16*16+cl][tap]
    pack_w_k<<<(216 * 512 + 255) / 256, 256, 0, stream>>>(
        w_off, wA1, 192, 3456, 144, 144, 16, 1, 9, 216 * 512);
    pack_w_k<<<(108 * 512 + 255) / 256, 256, 0, stream>>>(
        w_co, wA2, 108, 1728, 144, 144, 16, 1, 9, 108 * 512);
    // dcn (c16-outer order): k = c16*144 + kt*16 + cl -> w[o][c16*16+cl][kt]
    pack_w_k<<<(108 * 512 + 255) / 256, 256, 0, stream>>>(
        w_dcn, wA3, 192, 1728, 144, 144, 16, 1, 9, 108 * 512);

    // conv1: xg [48 grp] -> fg [24 grp bf16]
    conv_g_k<3, 24, true><<<dim3(2, HH, BB), 256, 0, stream>>>(xg, wA1, b_off, fg, 192);
    // conv2: fg [24 grp] -> offb [108 planar f32]
    conv_g_k<2, 12, false><<<dim3(2, HH, BB), 256, 0, stream>>>(fg, wA2, b_co, offb, 108);
    // fused deform-sample + einsum (barrier-free)
    dcn_g_k<<<dim3(4, HH, BB), 128, 0, stream>>>(xg, offb, wA3, b_dcn, out);
}